// Round 17
// baseline (329.471 us; speedup 1.0000x reference)
//
#include <hip/hip_runtime.h>
#include <hip/hip_bf16.h>
#include <hip/hip_fp16.h>
#include <math.h>

// Problem constants
#define BB 4
#define NN 4096
#define EE 256
#define HH 1024
#define NW 12
#define NL 13
#define MM (BB * NN)   // 16384 rows

typedef __attribute__((ext_vector_type(8))) short short8;   // 8x16b (4 VGPRs)
typedef __attribute__((ext_vector_type(4))) float f32x4;
typedef __attribute__((ext_vector_type(2))) _Float16 h2;    // packed f16 pair
typedef __attribute__((ext_vector_type(8))) _Float16 half8; // f16 MFMA frag

// Fast gelu, f32 scalar: x*sigmoid(1.5957691(x+0.044715x^3)), exp2 form.
__device__ __forceinline__ float gelu_fast(float x) {
    float t = __builtin_fmaf(0.044715f, x * x, 1.0f);
    float e = __builtin_amdgcn_exp2f(-2.3021193f * (x * t));
    return x * __builtin_amdgcn_rcpf(1.0f + e);
}

// Packed-f16 gelu on a pair of f32 inputs -> packed f16 pair bits (r15: -7us).
__device__ __forceinline__ unsigned gelu2_f16(float a, float b) {
    const h2 C1 = {(_Float16)-2.3021193f, (_Float16)-2.3021193f};
    const h2 C2 = {(_Float16)0.044715f, (_Float16)0.044715f};
    const h2 ONE = {(_Float16)1.0f, (_Float16)1.0f};
    h2 x;
    asm("v_cvt_pkrtz_f16_f32 %0, %1, %2" : "=v"(x) : "v"(a), "v"(b));
    h2 x2 = x * x;
    h2 t  = C2 * x2 + ONE;          // v_pk_fma_f16
    h2 z  = (C1 * x) * t;
    __half2 es = h2exp2(__builtin_bit_cast(__half2, z));
    h2 d = ONE + __builtin_bit_cast(h2, es);
    __half2 rs = h2rcp(__builtin_bit_cast(__half2, d));
    h2 y = x * __builtin_bit_cast(h2, rs);
    return __builtin_bit_cast(unsigned, y);
}

// Arithmetic bf16 pack (r14-validated in chord).
__device__ __forceinline__ unsigned pack_bf16_rh(float a, float b) {
    unsigned ua = (__builtin_bit_cast(unsigned, a) + 0x8000u) >> 16;
    unsigned ub = (__builtin_bit_cast(unsigned, b) + 0x8000u) & 0xFFFF0000u;
    return ua | ub;
}

// HW packed f32->2xbf16 (RNE), 1 VALU op.
__device__ __forceinline__ unsigned cvt_pk_bf16(float a, float b) {
    unsigned r;
    asm("v_cvt_pk_bf16_f32 %0, %1, %2" : "=v"(r) : "v"(a), "v"(b));
    return r;
}

__device__ __forceinline__ void unpack2(unsigned u, float& lo, float& hi) {
    lo = __builtin_bit_cast(float, u << 16);
    hi = __builtin_bit_cast(float, u & 0xFFFF0000u);
}

__device__ __forceinline__ void load_lds16(const void* g, void* l) {
    __builtin_amdgcn_global_load_lds(
        (const __attribute__((address_space(1))) void*)g,
        (__attribute__((address_space(3))) void*)l, 16, 0, 0);
}

// ---------------------------------------------------------------------------
// bf16 MFMA GEMM (m97 structure). Used for gate gemm2 (K=1024).
// ---------------------------------------------------------------------------
template<typename OutT, bool GELU>
__global__ __launch_bounds__(256) void gemm_bf16(
    const __hip_bfloat16* __restrict__ A,   // M x K  row-major
    const __hip_bfloat16* __restrict__ Bt,  // N x K  row-major (pre-transposed)
    const float* __restrict__ bias,         // N
    OutT* __restrict__ C,                   // M x N
    int M, int N, int K)
{
    __shared__ __hip_bfloat16 As[128 * 32];
    __shared__ __hip_bfloat16 Bs[128 * 32];

    const int tid = threadIdx.x;
    const int w = tid >> 6, l = tid & 63;
    const int wr = w >> 1, wc = w & 1;       // 2x2 wave grid, each 64x64
    const int row0 = blockIdx.y * 128;
    const int col0 = blockIdx.x * 128;

    const int c0 = w * 64 + l;
    const int c1 = c0 + 256;
    const __hip_bfloat16* gA0 = A  + (size_t)(row0 + (c0 >> 2)) * K + (c0 & 3) * 8;
    const __hip_bfloat16* gA1 = A  + (size_t)(row0 + (c1 >> 2)) * K + (c1 & 3) * 8;
    const __hip_bfloat16* gB0 = Bt + (size_t)(col0 + (c0 >> 2)) * K + (c0 & 3) * 8;
    const __hip_bfloat16* gB1 = Bt + (size_t)(col0 + (c1 >> 2)) * K + (c1 & 3) * 8;
    char* dA0 = (char*)As + w * 1024;
    char* dA1 = (char*)As + w * 1024 + 4096;
    char* dB0 = (char*)Bs + w * 1024;
    char* dB1 = (char*)Bs + w * 1024 + 4096;

    const int lr = l & 15;
    const int lk = (l >> 4) * 8;

    f32x4 acc[4][4] = {};

    for (int k0 = 0; k0 < K; k0 += 32) {
        load_lds16(gA0 + k0, dA0);
        load_lds16(gA1 + k0, dA1);
        load_lds16(gB0 + k0, dB0);
        load_lds16(gB1 + k0, dB1);
        __syncthreads();

        short8 a[4], b[4];
        #pragma unroll
        for (int m = 0; m < 4; ++m)
            a[m] = *(const short8*)&As[(wr * 64 + m * 16 + lr) * 32 + lk];
        #pragma unroll
        for (int n = 0; n < 4; ++n)
            b[n] = *(const short8*)&Bs[(wc * 64 + n * 16 + lr) * 32 + lk];
        #pragma unroll
        for (int m = 0; m < 4; ++m)
            #pragma unroll
            for (int n = 0; n < 4; ++n)
                acc[m][n] = __builtin_amdgcn_mfma_f32_16x16x32_bf16(a[m], b[n], acc[m][n], 0, 0, 0);
        __syncthreads();
    }

    #pragma unroll
    for (int m = 0; m < 4; ++m) {
        #pragma unroll
        for (int n = 0; n < 4; ++n) {
            const int col = col0 + wc * 64 + n * 16 + lr;
            const float bv = bias[col];
            #pragma unroll
            for (int j = 0; j < 4; ++j) {
                const int row = row0 + wr * 64 + m * 16 + (l >> 4) * 4 + j;
                float v = acc[m][n][j] + bv;
                if (GELU) v = gelu_fast(v);
                if constexpr (sizeof(OutT) == 2)
                    C[(size_t)row * N + col] = __float2bfloat16(v);
                else
                    C[(size_t)row * N + col] = v;
            }
        }
    }
}

// ---------------------------------------------------------------------------
// Merged kernel: grid (MM/128, NW+1).
//   blockIdx.y <  NW : f-level body (r15/r16-validated 138us structure)
//   blockIdx.y == NW : gate gemm1 body (r14-validated structure), looping all
//                      16 64-col chunks -> identical per-block work shape.
// ---------------------------------------------------------------------------
__global__ __launch_bounds__(256, 3) void fgate_fused(
    const __hip_bfloat16* __restrict__ X,     // MM x EE (bf16)
    const __hip_bfloat16* __restrict__ W1t,   // NW x HH x EE (bf16, f levels)
    const float* __restrict__ b1,             // NW x HH
    const _Float16* __restrict__ W2t,         // NW x 16 x HH (f16)
    const float* __restrict__ b2,             // NW x NL
    float* __restrict__ Wall,                 // MM x NW x 16
    const __hip_bfloat16* __restrict__ Vb,    // MM x EE (gate input)
    const __hip_bfloat16* __restrict__ gW1t,  // HH x EE (gate W1)
    const float* __restrict__ g_b1,           // HH
    __hip_bfloat16* __restrict__ Whb)         // MM x HH (gate hidden out)
{
    __shared__ __hip_bfloat16 Bs[8 * 64 * 32];        // 32 KB [kk][row][32]
    __shared__ __align__(16) char Gb[4][4096];        // per-wave G [32r][64h]
    __shared__ float biasS[HH];                       // 4 KB (f body only)

    const int tid = threadIdx.x;
    const int w = tid >> 6, l = tid & 63;
    const int row0 = blockIdx.x * 128;
    const int lr = l & 15;
    const int g  = l >> 4;
    const int lk = g * 8;
    char* Gw = Gb[w];

    if (blockIdx.y < NW) {
        // ================= f-level body =================
        const int m_lv = blockIdx.y;
        const __hip_bfloat16* W1m = W1t + (size_t)m_lv * HH * EE;

        ((float4*)biasS)[tid] = ((const float4*)(b1 + (size_t)m_lv * HH))[tid];

        short8 xf[2][8];
        {
            const __hip_bfloat16* xp0 = X + (size_t)(row0 + w * 32 + lr) * EE + lk;
            #pragma unroll
            for (int kk = 0; kk < 8; ++kk) {
                xf[0][kk] = *(const short8*)(xp0 + kk * 32);
                xf[1][kk] = *(const short8*)(xp0 + 16 * EE + kk * 32);
            }
        }

        const _Float16* w2p = W2t + ((size_t)m_lv * 16 + lr) * HH + lk;
        f32x4 wacc0 = {}, wacc1 = {};

        #pragma unroll
        for (int rstep = 0; rstep < 8; ++rstep) {
            const int c = rstep * 256 + tid;
            load_lds16(W1m + (size_t)((c >> 2) & 63) * EE + (c >> 8) * 32 + (c & 3) * 8,
                       (char*)Bs + c * 16);
        }
        __syncthreads();

        #pragma unroll 1
        for (int ct = 0; ct < 16; ++ct) {
            f32x4 acc[4][2];
            #pragma unroll
            for (int ni = 0; ni < 4; ++ni) {
                const float4 bv = *(const float4*)&biasS[ct * 64 + ni * 16 + g * 4];
                const f32x4 bi = {bv.x, bv.y, bv.z, bv.w};
                acc[ni][0] = bi;
                acc[ni][1] = bi;
            }
            __builtin_amdgcn_s_setprio(1);
            #pragma unroll
            for (int kk = 0; kk < 8; ++kk) {
                short8 a[4];
                #pragma unroll
                for (int ni = 0; ni < 4; ++ni)
                    a[ni] = *(const short8*)((const char*)Bs +
                             (kk * 4096 + ni * 1024 + lr * 64 + g * 16));
                #pragma unroll
                for (int ni = 0; ni < 4; ++ni) {
                    acc[ni][0] = __builtin_amdgcn_mfma_f32_16x16x32_bf16(a[ni], xf[0][kk], acc[ni][0], 0, 0, 0);
                    acc[ni][1] = __builtin_amdgcn_mfma_f32_16x16x32_bf16(a[ni], xf[1][kk], acc[ni][1], 0, 0, 0);
                }
            }
            __builtin_amdgcn_s_setprio(0);
            __syncthreads();

            if (ct < 15) {
                const __hip_bfloat16* W1n = W1m + (size_t)(ct + 1) * 64 * EE;
                #pragma unroll
                for (int rstep = 0; rstep < 8; ++rstep) {
                    const int c = rstep * 256 + tid;
                    load_lds16(W1n + (size_t)((c >> 2) & 63) * EE + (c >> 8) * 32 + (c & 3) * 8,
                               (char*)Bs + c * 16);
                }
            }

            // gelu (packed f16) -> wave-private swizzled G (f16)
            #pragma unroll
            for (int ni = 0; ni < 4; ++ni) {
                #pragma unroll
                for (int mi = 0; mi < 2; ++mi) {
                    const int rloc = mi * 16 + lr;
                    uint2 pk;
                    pk.x = gelu2_f16(acc[ni][mi][0], acc[ni][mi][1]);
                    pk.y = gelu2_f16(acc[ni][mi][2], acc[ni][mi][3]);
                    const int byte = (rloc * 128 + (ni * 16 + g * 4) * 2) ^ ((rloc & 7) << 4);
                    *(uint2*)(Gw + byte) = pk;
                }
            }

            // mini-GEMM (f16): Wall-frag += W2t[ct k-range] x G
            #pragma unroll
            for (int ks2 = 0; ks2 < 2; ++ks2) {
                const half8 aw = *(const half8*)(w2p + ct * 64 + ks2 * 32);
                {
                    const int byte = (lr * 128 + (ks2 * 32 + lk) * 2) ^ ((lr & 7) << 4);
                    const half8 bg = *(const half8*)(Gw + byte);
                    wacc0 = __builtin_amdgcn_mfma_f32_16x16x32_f16(aw, bg, wacc0, 0, 0, 0);
                }
                {
                    const int rloc = 16 + lr;
                    const int byte = (rloc * 128 + (ks2 * 32 + lk) * 2) ^ ((rloc & 7) << 4);
                    const half8 bg = *(const half8*)(Gw + byte);
                    wacc1 = __builtin_amdgcn_mfma_f32_16x16x32_f16(aw, bg, wacc1, 0, 0, 0);
                }
            }
            __syncthreads();
        }

        const float* b2m = b2 + m_lv * NL;
        #pragma unroll
        for (int j = 0; j < 4; ++j) {
            const int lval = g * 4 + j;
            const float bv = (lval < NL) ? b2m[lval] : 0.f;
            {
                const int r = row0 + w * 32 + lr;
                Wall[((size_t)r * NW + m_lv) * 16 + lval] = wacc0[j] + bv;
            }
            {
                const int r = row0 + w * 32 + 16 + lr;
                Wall[((size_t)r * NW + m_lv) * 16 + lval] = wacc1[j] + bv;
            }
        }
    } else {
        // ================= gate gemm1 body =================
        short8 xf[2][8];
        {
            const __hip_bfloat16* xp0 = Vb + (size_t)(row0 + w * 32 + lr) * EE + lk;
            #pragma unroll
            for (int kk = 0; kk < 8; ++kk) {
                xf[0][kk] = *(const short8*)(xp0 + kk * 32);
                xf[1][kk] = *(const short8*)(xp0 + 16 * EE + kk * 32);
            }
        }

        #pragma unroll
        for (int rstep = 0; rstep < 8; ++rstep) {
            const int c = rstep * 256 + tid;
            load_lds16(gW1t + (size_t)((c >> 2) & 63) * EE + (c >> 8) * 32 + (c & 3) * 8,
                       (char*)Bs + c * 16);
        }
        __syncthreads();

        #pragma unroll 1
        for (int cc = 0; cc < 16; ++cc) {
            f32x4 acc[4][2];
            #pragma unroll
            for (int ni = 0; ni < 4; ++ni) {
                const float4 bv = *(const float4*)&g_b1[cc * 64 + ni * 16 + g * 4];
                const f32x4 bi = {bv.x, bv.y, bv.z, bv.w};
                acc[ni][0] = bi;
                acc[ni][1] = bi;
            }
            __builtin_amdgcn_s_setprio(1);
            #pragma unroll
            for (int kk = 0; kk < 8; ++kk) {
                short8 a[4];
                #pragma unroll
                for (int ni = 0; ni < 4; ++ni)
                    a[ni] = *(const short8*)((const char*)Bs +
                             (kk * 4096 + ni * 1024 + lr * 64 + g * 16));
                #pragma unroll
                for (int ni = 0; ni < 4; ++ni) {
                    acc[ni][0] = __builtin_amdgcn_mfma_f32_16x16x32_bf16(a[ni], xf[0][kk], acc[ni][0], 0, 0, 0);
                    acc[ni][1] = __builtin_amdgcn_mfma_f32_16x16x32_bf16(a[ni], xf[1][kk], acc[ni][1], 0, 0, 0);
                }
            }
            __builtin_amdgcn_s_setprio(0);
            __syncthreads();

            if (cc < 15) {
                const __hip_bfloat16* W1n = gW1t + (size_t)(cc + 1) * 64 * EE;
                #pragma unroll
                for (int rstep = 0; rstep < 8; ++rstep) {
                    const int c = rstep * 256 + tid;
                    load_lds16(W1n + (size_t)((c >> 2) & 63) * EE + (c >> 8) * 32 + (c & 3) * 8,
                               (char*)Bs + c * 16);
                }
            }

            // gelu (f32) -> bf16 (cvt_pk) -> wave-private swizzled G
            #pragma unroll
            for (int ni = 0; ni < 4; ++ni) {
                #pragma unroll
                for (int mi = 0; mi < 2; ++mi) {
                    const int rloc = mi * 16 + lr;
                    const float v0 = gelu_fast(acc[ni][mi][0]);
                    const float v1 = gelu_fast(acc[ni][mi][1]);
                    const float v2 = gelu_fast(acc[ni][mi][2]);
                    const float v3 = gelu_fast(acc[ni][mi][3]);
                    uint2 pk;
                    pk.x = cvt_pk_bf16(v0, v1);
                    pk.y = cvt_pk_bf16(v2, v3);
                    const int byte = (rloc * 128 + (ni * 16 + g * 4) * 2) ^ ((rloc & 7) << 4);
                    *(uint2*)(Gw + byte) = pk;
                }
            }

            // coalesced store: 4 passes x (8 rows x 128B); G is wave-private
            #pragma unroll
            for (int p = 0; p < 4; ++p) {
                const int rl = p * 8 + (l >> 3);
                const int hb = (l & 7) * 16;
                const uint4 v = *(const uint4*)(Gw + ((rl * 128 + hb) ^ ((rl & 7) << 4)));
                *(uint4*)((char*)(Whb + (size_t)(row0 + w * 32 + rl) * HH + cc * 64) + hb) = v;
            }
            __syncthreads();
        }
    }
}

// ---------------------------------------------------------------------------
// One prep kernel for ALL conversions/transposes.
// ---------------------------------------------------------------------------
struct bf4 { __hip_bfloat16 a, b, c, d; };

__device__ __forceinline__ void cvt_body(
    const float* __restrict__ in, __hip_bfloat16* __restrict__ out, int i)
{
    float4 v = ((const float4*)in)[i];
    bf4 o;
    o.a = __float2bfloat16(v.x); o.b = __float2bfloat16(v.y);
    o.c = __float2bfloat16(v.z); o.d = __float2bfloat16(v.w);
    ((bf4*)out)[i] = o;
}

__device__ __forceinline__ void transpose_body(
    const float* __restrict__ inB, __hip_bfloat16* __restrict__ outB,
    int K, int N, int bx, int by, float (*t)[33])
{
    const int n0 = bx * 32, k0 = by * 32;
    const int tx = threadIdx.x & 31, ty = threadIdx.x >> 5;  // 32 x 8
    #pragma unroll
    for (int i = 0; i < 32; i += 8)
        t[ty + i][tx] = inB[(size_t)(k0 + ty + i) * N + n0 + tx];
    __syncthreads();
    #pragma unroll
    for (int i = 0; i < 32; i += 8)
        outB[(size_t)(n0 + ty + i) * K + k0 + tx] = __float2bfloat16(t[tx][ty + i]);
}

__global__ __launch_bounds__(256) void prep_all(
    const float* __restrict__ V, const float* __restrict__ input,
    const float* __restrict__ g_W1, const float* __restrict__ g_W2,
    const float* __restrict__ f_W1, const float* __restrict__ f_W2,
    __hip_bfloat16* __restrict__ Vb, __hip_bfloat16* __restrict__ Xb,
    __hip_bfloat16* __restrict__ gW1t, __hip_bfloat16* __restrict__ gW2t,
    __hip_bfloat16* __restrict__ fW1t, _Float16* __restrict__ W2tA)
{
    __shared__ float t[32][33];
    const int bid = blockIdx.x;
    const int tid = threadIdx.x;

    if (bid < 4096) {
        cvt_body(V, Vb, bid * 256 + tid);
    } else if (bid < 8192) {
        cvt_body(input, Xb, (bid - 4096) * 256 + tid);
    } else if (bid < 8448) {
        const int b2 = bid - 8192;                   // g_W1: grid (32, 8)
        transpose_body(g_W1, gW1t, EE, HH, b2 & 31, b2 >> 5, t);
    } else if (bid < 8704) {
        const int b2 = bid - 8448;                   // g_W2: grid (8, 32)
        transpose_body(g_W2, gW2t, HH, EE, b2 & 7, b2 >> 3, t);
    } else if (bid < 11776) {
        const int b2 = bid - 8704;                   // f_W1: 12 x (32, 8)
        const int z = b2 >> 8, r = b2 & 255;
        transpose_body(f_W1 + (size_t)z * EE * HH, fW1t + (size_t)z * HH * EE,
                       EE, HH, r & 31, r >> 5, t);
    } else {
        const int idx = (bid - 11776) * 256 + tid;   // w2t: NW*16*HH elems, f16
        const int m = idx >> 14;
        const int n = (idx >> 10) & 15;
        const int h = idx & 1023;
        const float v = (n < NL) ? f_W2[((size_t)m * HH + h) * NL + n] : 0.f;
        W2tA[idx] = (_Float16)v;
    }
}

// ---------------------------------------------------------------------------
// Chord step: bf16 state, f32 accumulation, 4 rows/thread interleaved,
// XCD-chunked block mapping: XCD k owns rows [2048k, 2048(k+1)) so all +-2^l
// gathers stay in that batch's 2 MB window (fits the per-XCD 4 MB L2).
// ---------------------------------------------------------------------------
template<bool LAST>
__global__ __launch_bounds__(256) void chord_bf16(
    const uint2* __restrict__ Vin,   // MM x 64 (4 bf16 per lane-slot)
    const float* __restrict__ Wall,  // MM x NW x 16
    void* __restrict__ Vout,         // bf16 (MM x 64 uint2) or f32 (float4)
    int m)
{
    const int t = threadIdx.x;
    const int rq = t >> 6;
    const int e = t & 63;
    const int bid = blockIdx.x;                       // 1024 blocks
    const int r0 = ((bid & 7) * 128 + (bid >> 3)) * 16 + rq;
    const int b = r0 >> 12;                  // block never crosses a batch
    const size_t base = (size_t)(b << 12) * 64 + e;

    int n[4];
    const float* wrow[4];
    float a[4][4];
    #pragma unroll
    for (int i = 0; i < 4; ++i) {
        const int r = r0 + i * 4;
        n[i] = r & (NN - 1);
        wrow[i] = Wall + ((size_t)r * NW + m) * 16;
        const uint2 s = Vin[(size_t)r * 64 + e];
        unpack2(s.x, a[i][0], a[i][1]);
        unpack2(s.y, a[i][2], a[i][3]);
    }

    #pragma unroll
    for (int l = 0; l < NL; ++l) {
        const int off = (l == 0) ? 0 : (1 << (l - 1));
        uint2 x[4];
        float wv[4];
        #pragma unroll
        for (int i = 0; i < 4; ++i) {
            const int cn = (n[i] + off) & (NN - 1);
            x[i] = Vin[base + (size_t)cn * 64];
            wv[i] = wrow[i][l];
        }
        #pragma unroll
        for (int i = 0; i < 4; ++i) {
            float x0, x1, x2, x3;
            unpack2(x[i].x, x0, x1);
            unpack2(x[i].y, x2, x3);
            a[i][0] = __builtin_fmaf(wv[i], x0, a[i][0]);
            a[i][1] = __builtin_fmaf(wv[i], x1, a[i][1]);
            a[i][2] = __builtin_fmaf(wv[i], x2, a[i][2]);
            a[i][3] = __builtin_fmaf(wv[i], x3, a[i][3]);
        }
    }

    #pragma unroll
    for (int i = 0; i < 4; ++i) {
        const int r = r0 + i * 4;
        if constexpr (LAST) {
            float4 o = {a[i][0], a[i][1], a[i][2], a[i][3]};
            ((float4*)Vout)[(size_t)r * 64 + e] = o;
        } else {
            uint2 o;
            o.x = pack_bf16_rh(a[i][0], a[i][1]);
            o.y = pack_bf16_rh(a[i][2], a[i][3]);
            ((uint2*)Vout)[(size_t)r * 64 + e] = o;
        }
    }
}

// ---------------------------------------------------------------------------
extern "C" void kernel_launch(void* const* d_in, const int* in_sizes, int n_in,
                              void* d_out, int out_size, void* d_ws, size_t ws_size,
                              hipStream_t stream)
{
    const float* V      = (const float*)d_in[0];
    const float* input  = (const float*)d_in[1];
    const float* g_W1   = (const float*)d_in[2];
    const float* g_b1   = (const float*)d_in[3];
    const float* g_W2   = (const float*)d_in[4];
    const float* g_b2   = (const float*)d_in[5];
    const float* f_W1   = (const float*)d_in[6];
    const float* f_b1   = (const float*)d_in[7];
    const float* f_W2   = (const float*)d_in[8];
    const float* f_b2   = (const float*)d_in[9];
    float* out = (float*)d_out;

    char* ws = (char*)d_ws;
    size_t o = 0;
    __hip_bfloat16* Vb     = (__hip_bfloat16*)(ws + o); o += (size_t)MM * EE * 2;        // 8 MB
    __hip_bfloat16* Xb     = (__hip_bfloat16*)(ws + o); o += (size_t)MM * EE * 2;        // 8 MB
    __hip_bfloat16* gW1t   = (__hip_bfloat16*)(ws + o); o += (size_t)HH * EE * 2;        // 512 KB
    __hip_bfloat16* gW2t   = (__hip_bfloat16*)(ws + o); o += (size_t)EE * HH * 2;        // 512 KB
    __hip_bfloat16* fW1t   = (__hip_bfloat16*)(ws + o); o += (size_t)NW * HH * EE * 2;   // 6 MB
    _Float16*       W2tA   = (_Float16*)(ws + o);       o += (size_t)NW * 16 * HH * 2;   // 384 KB
    __hip_bfloat16* Whb    = (__hip_bfloat16*)(ws + o); o += (size_t)MM * HH * 2;        // 32 MB (gate only)
    float*          Wall   = (float*)(ws + o);          o += (size_t)MM * NW * 16 * 4;   // 12 MB
    __hip_bfloat16* Vg0    = (__hip_bfloat16*)(ws + o); o += (size_t)MM * EE * 2;        // 8 MB
    __hip_bfloat16* Vg1    = (__hip_bfloat16*)(ws + o); o += (size_t)MM * EE * 2;        // 8 MB

    dim3 blk(256);

    // 0. ALL dtype conversion / weight transposes in one launch
    prep_all<<<12544, blk, 0, stream>>>(V, input, g_W1, g_W2, f_W1, f_W2,
                                        Vb, Xb, gW1t, gW2t, fW1t, W2tA);

    // 1. Merged: all 12 f-levels + gate gemm1 in ONE launch (grid 128 x 13)
    fgate_fused<<<dim3(MM / 128, NW + 1), blk, 0, stream>>>(
        Xb, fW1t, f_b1, W2tA, f_b2, Wall, Vb, gW1t, g_b1, Whb);

    // 2. Gate gemm2 (K=1024), bf16 MFMA, bf16 out -> Vg0
    gemm_bf16<__hip_bfloat16, false><<<dim3(EE / 128, MM / 128), blk, 0, stream>>>(
        Whb, gW2t, g_b2, Vg0, MM, EE, HH);

    // 3. 12 sequential chord steps, stream-ordered; final widens to f32 out
    const __hip_bfloat16* cur = Vg0;
    __hip_bfloat16* nxt = Vg1;
    for (int m = 0; m < NW - 1; ++m) {
        chord_bf16<false><<<MM / 16, blk, 0, stream>>>(
            (const uint2*)cur, Wall, nxt, m);
        __hip_bfloat16* tswap = (__hip_bfloat16*)cur;
        cur = nxt;
        nxt = tswap;
    }
    chord_bf16<true><<<MM / 16, blk, 0, stream>>>(
        (const uint2*)cur, Wall, out, NW - 1);
}

// Round 18
// 328.673 us; speedup vs baseline: 1.0024x; 1.0024x over previous
//
#include <hip/hip_runtime.h>
#include <hip/hip_bf16.h>
#include <hip/hip_fp16.h>
#include <math.h>

// Problem constants
#define BB 4
#define NN 4096
#define EE 256
#define HH 1024
#define NW 12
#define NL 13
#define MM (BB * NN)   // 16384 rows

typedef __attribute__((ext_vector_type(8))) short short8;   // 8x16b (4 VGPRs)
typedef __attribute__((ext_vector_type(4))) float f32x4;
typedef __attribute__((ext_vector_type(2))) _Float16 h2;    // packed f16 pair
typedef __attribute__((ext_vector_type(8))) _Float16 half8; // f16 MFMA frag

// Fast gelu, f32 scalar: x*sigmoid(1.5957691(x+0.044715x^3)), exp2 form.
__device__ __forceinline__ float gelu_fast(float x) {
    float t = __builtin_fmaf(0.044715f, x * x, 1.0f);
    float e = __builtin_amdgcn_exp2f(-2.3021193f * (x * t));
    return x * __builtin_amdgcn_rcpf(1.0f + e);
}

// Packed-f16 gelu on a pair of f32 inputs -> packed f16 pair bits (r15: -7us).
__device__ __forceinline__ unsigned gelu2_f16(float a, float b) {
    const h2 C1 = {(_Float16)-2.3021193f, (_Float16)-2.3021193f};
    const h2 C2 = {(_Float16)0.044715f, (_Float16)0.044715f};
    const h2 ONE = {(_Float16)1.0f, (_Float16)1.0f};
    h2 x;
    asm("v_cvt_pkrtz_f16_f32 %0, %1, %2" : "=v"(x) : "v"(a), "v"(b));
    h2 x2 = x * x;
    h2 t  = C2 * x2 + ONE;          // v_pk_fma_f16
    h2 z  = (C1 * x) * t;
    __half2 es = h2exp2(__builtin_bit_cast(__half2, z));
    h2 d = ONE + __builtin_bit_cast(h2, es);
    __half2 rs = h2rcp(__builtin_bit_cast(__half2, d));
    h2 y = x * __builtin_bit_cast(h2, rs);
    return __builtin_bit_cast(unsigned, y);
}

// Arithmetic bf16 pack (r14-validated in chord).
__device__ __forceinline__ unsigned pack_bf16_rh(float a, float b) {
    unsigned ua = (__builtin_bit_cast(unsigned, a) + 0x8000u) >> 16;
    unsigned ub = (__builtin_bit_cast(unsigned, b) + 0x8000u) & 0xFFFF0000u;
    return ua | ub;
}

// HW packed f32->2xbf16 (RNE), 1 VALU op.
__device__ __forceinline__ unsigned cvt_pk_bf16(float a, float b) {
    unsigned r;
    asm("v_cvt_pk_bf16_f32 %0, %1, %2" : "=v"(r) : "v"(a), "v"(b));
    return r;
}

__device__ __forceinline__ void unpack2(unsigned u, float& lo, float& hi) {
    lo = __builtin_bit_cast(float, u << 16);
    hi = __builtin_bit_cast(float, u & 0xFFFF0000u);
}

__device__ __forceinline__ void load_lds16(const void* g, void* l) {
    __builtin_amdgcn_global_load_lds(
        (const __attribute__((address_space(1))) void*)g,
        (__attribute__((address_space(3))) void*)l, 16, 0, 0);
}

// ---------------------------------------------------------------------------
// bf16 MFMA GEMM (m97 structure). Used for gate gemm2 (K=1024).
// ---------------------------------------------------------------------------
template<typename OutT, bool GELU>
__global__ __launch_bounds__(256) void gemm_bf16(
    const __hip_bfloat16* __restrict__ A,   // M x K  row-major
    const __hip_bfloat16* __restrict__ Bt,  // N x K  row-major (pre-transposed)
    const float* __restrict__ bias,         // N
    OutT* __restrict__ C,                   // M x N
    int M, int N, int K)
{
    __shared__ __hip_bfloat16 As[128 * 32];
    __shared__ __hip_bfloat16 Bs[128 * 32];

    const int tid = threadIdx.x;
    const int w = tid >> 6, l = tid & 63;
    const int wr = w >> 1, wc = w & 1;       // 2x2 wave grid, each 64x64
    const int row0 = blockIdx.y * 128;
    const int col0 = blockIdx.x * 128;

    const int c0 = w * 64 + l;
    const int c1 = c0 + 256;
    const __hip_bfloat16* gA0 = A  + (size_t)(row0 + (c0 >> 2)) * K + (c0 & 3) * 8;
    const __hip_bfloat16* gA1 = A  + (size_t)(row0 + (c1 >> 2)) * K + (c1 & 3) * 8;
    const __hip_bfloat16* gB0 = Bt + (size_t)(col0 + (c0 >> 2)) * K + (c0 & 3) * 8;
    const __hip_bfloat16* gB1 = Bt + (size_t)(col0 + (c1 >> 2)) * K + (c1 & 3) * 8;
    char* dA0 = (char*)As + w * 1024;
    char* dA1 = (char*)As + w * 1024 + 4096;
    char* dB0 = (char*)Bs + w * 1024;
    char* dB1 = (char*)Bs + w * 1024 + 4096;

    const int lr = l & 15;
    const int lk = (l >> 4) * 8;

    f32x4 acc[4][4] = {};

    for (int k0 = 0; k0 < K; k0 += 32) {
        load_lds16(gA0 + k0, dA0);
        load_lds16(gA1 + k0, dA1);
        load_lds16(gB0 + k0, dB0);
        load_lds16(gB1 + k0, dB1);
        __syncthreads();

        short8 a[4], b[4];
        #pragma unroll
        for (int m = 0; m < 4; ++m)
            a[m] = *(const short8*)&As[(wr * 64 + m * 16 + lr) * 32 + lk];
        #pragma unroll
        for (int n = 0; n < 4; ++n)
            b[n] = *(const short8*)&Bs[(wc * 64 + n * 16 + lr) * 32 + lk];
        #pragma unroll
        for (int m = 0; m < 4; ++m)
            #pragma unroll
            for (int n = 0; n < 4; ++n)
                acc[m][n] = __builtin_amdgcn_mfma_f32_16x16x32_bf16(a[m], b[n], acc[m][n], 0, 0, 0);
        __syncthreads();
    }

    #pragma unroll
    for (int m = 0; m < 4; ++m) {
        #pragma unroll
        for (int n = 0; n < 4; ++n) {
            const int col = col0 + wc * 64 + n * 16 + lr;
            const float bv = bias[col];
            #pragma unroll
            for (int j = 0; j < 4; ++j) {
                const int row = row0 + wr * 64 + m * 16 + (l >> 4) * 4 + j;
                float v = acc[m][n][j] + bv;
                if (GELU) v = gelu_fast(v);
                if constexpr (sizeof(OutT) == 2)
                    C[(size_t)row * N + col] = __float2bfloat16(v);
                else
                    C[(size_t)row * N + col] = v;
            }
        }
    }
}

// ---------------------------------------------------------------------------
// Gate gemm1, A-in-registers (r14/r16-validated): Wh(bf16) = gelu(Vb@W1+b1).
// ---------------------------------------------------------------------------
__global__ __launch_bounds__(256, 3) void gemm1_areg(
    const __hip_bfloat16* __restrict__ A,     // MM x EE (Vb)
    const __hip_bfloat16* __restrict__ W1t,   // HH x EE
    const float* __restrict__ b1,             // HH
    __hip_bfloat16* __restrict__ Wh)          // MM x HH
{
    __shared__ __hip_bfloat16 Bs[8 * 64 * 32];   // 32 KB [kk][row][32]
    __shared__ __align__(16) char Gb[4][4096];   // per-wave G [32r][64h]

    const int tid = threadIdx.x;
    const int w = tid >> 6, l = tid & 63;
    const int row0 = blockIdx.x * 128;
    const int col0 = blockIdx.y * 128;
    const int lr = l & 15, g = l >> 4, lk = g * 8;

    short8 xf[2][8];
    {
        const __hip_bfloat16* xp0 = A + (size_t)(row0 + w * 32 + lr) * EE + lk;
        #pragma unroll
        for (int kk = 0; kk < 8; ++kk) {
            xf[0][kk] = *(const short8*)(xp0 + kk * 32);
            xf[1][kk] = *(const short8*)(xp0 + 16 * EE + kk * 32);
        }
    }
    char* Gw = Gb[w];

    #pragma unroll
    for (int rstep = 0; rstep < 8; ++rstep) {
        const int c = rstep * 256 + tid;
        load_lds16(W1t + (size_t)(col0 + ((c >> 2) & 63)) * EE + (c >> 8) * 32 + (c & 3) * 8,
                   (char*)Bs + c * 16);
    }
    __syncthreads();

    #pragma unroll 1
    for (int ct = 0; ct < 2; ++ct) {
        f32x4 acc[4][2];
        #pragma unroll
        for (int ni = 0; ni < 4; ++ni) {
            const float4 bv = *(const float4*)&b1[col0 + ct * 64 + ni * 16 + g * 4];
            const f32x4 bi = {bv.x, bv.y, bv.z, bv.w};
            acc[ni][0] = bi;
            acc[ni][1] = bi;
        }
        __builtin_amdgcn_s_setprio(1);
        #pragma unroll
        for (int kk = 0; kk < 8; ++kk) {
            short8 a[4];
            #pragma unroll
            for (int ni = 0; ni < 4; ++ni)
                a[ni] = *(const short8*)((const char*)Bs +
                         (kk * 4096 + ni * 1024 + lr * 64 + g * 16));
            #pragma unroll
            for (int ni = 0; ni < 4; ++ni) {
                acc[ni][0] = __builtin_amdgcn_mfma_f32_16x16x32_bf16(a[ni], xf[0][kk], acc[ni][0], 0, 0, 0);
                acc[ni][1] = __builtin_amdgcn_mfma_f32_16x16x32_bf16(a[ni], xf[1][kk], acc[ni][1], 0, 0, 0);
            }
        }
        __builtin_amdgcn_s_setprio(0);
        __syncthreads();

        if (ct == 0) {
            #pragma unroll
            for (int rstep = 0; rstep < 8; ++rstep) {
                const int c = rstep * 256 + tid;
                load_lds16(W1t + (size_t)(col0 + 64 + ((c >> 2) & 63)) * EE + (c >> 8) * 32 + (c & 3) * 8,
                           (char*)Bs + c * 16);
            }
        }

        // gelu (f32) -> bf16 (cvt_pk) -> wave-private swizzled G
        #pragma unroll
        for (int ni = 0; ni < 4; ++ni) {
            #pragma unroll
            for (int mi = 0; mi < 2; ++mi) {
                const int rloc = mi * 16 + lr;
                const float v0 = gelu_fast(acc[ni][mi][0]);
                const float v1 = gelu_fast(acc[ni][mi][1]);
                const float v2 = gelu_fast(acc[ni][mi][2]);
                const float v3 = gelu_fast(acc[ni][mi][3]);
                uint2 pk;
                pk.x = cvt_pk_bf16(v0, v1);
                pk.y = cvt_pk_bf16(v2, v3);
                const int byte = (rloc * 128 + (ni * 16 + g * 4) * 2) ^ ((rloc & 7) << 4);
                *(uint2*)(Gw + byte) = pk;
            }
        }

        // coalesced store: 4 passes x (8 rows x 128B); G is wave-private
        #pragma unroll
        for (int p = 0; p < 4; ++p) {
            const int rl = p * 8 + (l >> 3);
            const int hb = (l & 7) * 16;
            const uint4 v = *(const uint4*)(Gw + ((rl * 128 + hb) ^ ((rl & 7) << 4)));
            *(uint4*)((char*)(Wh + (size_t)(row0 + w * 32 + rl) * HH + col0 + ct * 64) + hb) = v;
        }
        __syncthreads();
    }
}

// ---------------------------------------------------------------------------
// Fused f-level kernel (r15/r16-validated 138 us): big GEMM bf16,
// gelu packed-f16, mini-GEMM f16.
// ---------------------------------------------------------------------------
__global__ __launch_bounds__(256, 3) void f_fused(
    const __hip_bfloat16* __restrict__ X,     // MM x EE (bf16)
    const __hip_bfloat16* __restrict__ W1t,   // NW x HH x EE (bf16)
    const float* __restrict__ b1,             // NW x HH
    const _Float16* __restrict__ W2t,         // NW x 16 x HH (f16)
    const float* __restrict__ b2,             // NW x NL
    float* __restrict__ Wall)                 // MM x NW x 16
{
    __shared__ __hip_bfloat16 Bs[8 * 64 * 32];        // 32 KB [kk][row][32]
    __shared__ __align__(16) char Gb[4][4096];        // per-wave G [32r][64h] f16
    __shared__ float biasS[HH];                       // 4 KB

    const int tid = threadIdx.x;
    const int w = tid >> 6, l = tid & 63;
    const int row0 = blockIdx.x * 128;
    const int m_lv = blockIdx.y;
    const int lr = l & 15;
    const int g  = l >> 4;
    const int lk = g * 8;

    const __hip_bfloat16* W1m = W1t + (size_t)m_lv * HH * EE;

    ((float4*)biasS)[tid] = ((const float4*)(b1 + (size_t)m_lv * HH))[tid];

    short8 xf[2][8];
    {
        const __hip_bfloat16* xp0 = X + (size_t)(row0 + w * 32 + lr) * EE + lk;
        #pragma unroll
        for (int kk = 0; kk < 8; ++kk) {
            xf[0][kk] = *(const short8*)(xp0 + kk * 32);
            xf[1][kk] = *(const short8*)(xp0 + 16 * EE + kk * 32);
        }
    }

    const _Float16* w2p = W2t + ((size_t)m_lv * 16 + lr) * HH + lk;
    char* Gw = Gb[w];

    f32x4 wacc0 = {}, wacc1 = {};

    #pragma unroll
    for (int rstep = 0; rstep < 8; ++rstep) {
        const int c = rstep * 256 + tid;
        load_lds16(W1m + (size_t)((c >> 2) & 63) * EE + (c >> 8) * 32 + (c & 3) * 8,
                   (char*)Bs + c * 16);
    }
    __syncthreads();

    #pragma unroll 1
    for (int ct = 0; ct < 16; ++ct) {
        // acc C-in = bias
        f32x4 acc[4][2];
        #pragma unroll
        for (int ni = 0; ni < 4; ++ni) {
            const float4 bv = *(const float4*)&biasS[ct * 64 + ni * 16 + g * 4];
            const f32x4 bi = {bv.x, bv.y, bv.z, bv.w};
            acc[ni][0] = bi;
            acc[ni][1] = bi;
        }
        __builtin_amdgcn_s_setprio(1);
        #pragma unroll
        for (int kk = 0; kk < 8; ++kk) {
            short8 a[4];
            #pragma unroll
            for (int ni = 0; ni < 4; ++ni)
                a[ni] = *(const short8*)((const char*)Bs +
                         (kk * 4096 + ni * 1024 + lr * 64 + g * 16));
            #pragma unroll
            for (int ni = 0; ni < 4; ++ni) {
                acc[ni][0] = __builtin_amdgcn_mfma_f32_16x16x32_bf16(a[ni], xf[0][kk], acc[ni][0], 0, 0, 0);
                acc[ni][1] = __builtin_amdgcn_mfma_f32_16x16x32_bf16(a[ni], xf[1][kk], acc[ni][1], 0, 0, 0);
            }
        }
        __builtin_amdgcn_s_setprio(0);
        __syncthreads();                       // all waves done reading Bs

        if (ct < 15) {
            const __hip_bfloat16* W1n = W1m + (size_t)(ct + 1) * 64 * EE;
            #pragma unroll
            for (int rstep = 0; rstep < 8; ++rstep) {
                const int c = rstep * 256 + tid;
                load_lds16(W1n + (size_t)((c >> 2) & 63) * EE + (c >> 8) * 32 + (c & 3) * 8,
                           (char*)Bs + c * 16);
            }
        }

        // gelu (packed f16) -> wave-private swizzled G (f16)
        #pragma unroll
        for (int ni = 0; ni < 4; ++ni) {
            #pragma unroll
            for (int mi = 0; mi < 2; ++mi) {
                const int rloc = mi * 16 + lr;
                uint2 pk;
                pk.x = gelu2_f16(acc[ni][mi][0], acc[ni][mi][1]);
                pk.y = gelu2_f16(acc[ni][mi][2], acc[ni][mi][3]);
                const int byte = (rloc * 128 + (ni * 16 + g * 4) * 2) ^ ((rloc & 7) << 4);
                *(uint2*)(Gw + byte) = pk;
            }
        }

        // mini-GEMM (f16): Wall-frag += W2t[ct k-range] x G
        #pragma unroll
        for (int ks2 = 0; ks2 < 2; ++ks2) {
            const half8 aw = *(const half8*)(w2p + ct * 64 + ks2 * 32);
            {
                const int byte = (lr * 128 + (ks2 * 32 + lk) * 2) ^ ((lr & 7) << 4);
                const half8 bg = *(const half8*)(Gw + byte);
                wacc0 = __builtin_amdgcn_mfma_f32_16x16x32_f16(aw, bg, wacc0, 0, 0, 0);
            }
            {
                const int rloc = 16 + lr;
                const int byte = (rloc * 128 + (ks2 * 32 + lk) * 2) ^ ((rloc & 7) << 4);
                const half8 bg = *(const half8*)(Gw + byte);
                wacc1 = __builtin_amdgcn_mfma_f32_16x16x32_f16(aw, bg, wacc1, 0, 0, 0);
            }
        }
        __syncthreads();                       // staging drained; Bs ready
    }

    const float* b2m = b2 + m_lv * NL;
    #pragma unroll
    for (int j = 0; j < 4; ++j) {
        const int lval = g * 4 + j;
        const float bv = (lval < NL) ? b2m[lval] : 0.f;
        {
            const int r = row0 + w * 32 + lr;
            Wall[((size_t)r * NW + m_lv) * 16 + lval] = wacc0[j] + bv;
        }
        {
            const int r = row0 + w * 32 + 16 + lr;
            Wall[((size_t)r * NW + m_lv) * 16 + lval] = wacc1[j] + bv;
        }
    }
}

// ---------------------------------------------------------------------------
// One prep kernel for ALL conversions/transposes.
// ---------------------------------------------------------------------------
struct bf4 { __hip_bfloat16 a, b, c, d; };

__device__ __forceinline__ void cvt_body(
    const float* __restrict__ in, __hip_bfloat16* __restrict__ out, int i)
{
    float4 v = ((const float4*)in)[i];
    bf4 o;
    o.a = __float2bfloat16(v.x); o.b = __float2bfloat16(v.y);
    o.c = __float2bfloat16(v.z); o.d = __float2bfloat16(v.w);
    ((bf4*)out)[i] = o;
}

__device__ __forceinline__ void transpose_body(
    const float* __restrict__ inB, __hip_bfloat16* __restrict__ outB,
    int K, int N, int bx, int by, float (*t)[33])
{
    const int n0 = bx * 32, k0 = by * 32;
    const int tx = threadIdx.x & 31, ty = threadIdx.x >> 5;  // 32 x 8
    #pragma unroll
    for (int i = 0; i < 32; i += 8)
        t[ty + i][tx] = inB[(size_t)(k0 + ty + i) * N + n0 + tx];
    __syncthreads();
    #pragma unroll
    for (int i = 0; i < 32; i += 8)
        outB[(size_t)(n0 + ty + i) * K + k0 + tx] = __float2bfloat16(t[tx][ty + i]);
}

__global__ __launch_bounds__(256) void prep_all(
    const float* __restrict__ V, const float* __restrict__ input,
    const float* __restrict__ g_W1, const float* __restrict__ g_W2,
    const float* __restrict__ f_W1, const float* __restrict__ f_W2,
    __hip_bfloat16* __restrict__ Vb, __hip_bfloat16* __restrict__ Xb,
    __hip_bfloat16* __restrict__ gW1t, __hip_bfloat16* __restrict__ gW2t,
    __hip_bfloat16* __restrict__ fW1t, _Float16* __restrict__ W2tA)
{
    __shared__ float t[32][33];
    const int bid = blockIdx.x;
    const int tid = threadIdx.x;

    if (bid < 4096) {
        cvt_body(V, Vb, bid * 256 + tid);
    } else if (bid < 8192) {
        cvt_body(input, Xb, (bid - 4096) * 256 + tid);
    } else if (bid < 8448) {
        const int b2 = bid - 8192;                   // g_W1: grid (32, 8)
        transpose_body(g_W1, gW1t, EE, HH, b2 & 31, b2 >> 5, t);
    } else if (bid < 8704) {
        const int b2 = bid - 8448;                   // g_W2: grid (8, 32)
        transpose_body(g_W2, gW2t, HH, EE, b2 & 7, b2 >> 3, t);
    } else if (bid < 11776) {
        const int b2 = bid - 8704;                   // f_W1: 12 x (32, 8)
        const int z = b2 >> 8, r = b2 & 255;
        transpose_body(f_W1 + (size_t)z * EE * HH, fW1t + (size_t)z * HH * EE,
                       EE, HH, r & 31, r >> 5, t);
    } else {
        const int idx = (bid - 11776) * 256 + tid;   // w2t: NW*16*HH elems, f16
        const int m = idx >> 14;
        const int n = (idx >> 10) & 15;
        const int h = idx & 1023;
        const float v = (n < NL) ? f_W2[((size_t)m * HH + h) * NL + n] : 0.f;
        W2tA[idx] = (_Float16)v;
    }
}

// ---------------------------------------------------------------------------
// Chord step: bf16 state, f32 accumulation, 4 rows/thread interleaved,
// XCD-chunked block mapping (r17-validated, ~-9us aggregate): XCD k owns rows
// [2048k, 2048(k+1)) so all +-2^l gathers stay in that batch's 2 MB window
// (fits the per-XCD 4 MB L2) and each XCD re-reads its own last-step writes.
// ---------------------------------------------------------------------------
template<bool LAST>
__global__ __launch_bounds__(256) void chord_bf16(
    const uint2* __restrict__ Vin,   // MM x 64 (4 bf16 per lane-slot)
    const float* __restrict__ Wall,  // MM x NW x 16
    void* __restrict__ Vout,         // bf16 (MM x 64 uint2) or f32 (float4)
    int m)
{
    const int t = threadIdx.x;
    const int rq = t >> 6;
    const int e = t & 63;
    const int bid = blockIdx.x;                       // 1024 blocks
    const int r0 = ((bid & 7) * 128 + (bid >> 3)) * 16 + rq;
    const int b = r0 >> 12;                  // block never crosses a batch
    const size_t base = (size_t)(b << 12) * 64 + e;

    int n[4];
    const float* wrow[4];
    float a[4][4];
    #pragma unroll
    for (int i = 0; i < 4; ++i) {
        const int r = r0 + i * 4;
        n[i] = r & (NN - 1);
        wrow[i] = Wall + ((size_t)r * NW + m) * 16;
        const uint2 s = Vin[(size_t)r * 64 + e];
        unpack2(s.x, a[i][0], a[i][1]);
        unpack2(s.y, a[i][2], a[i][3]);
    }

    #pragma unroll
    for (int l = 0; l < NL; ++l) {
        const int off = (l == 0) ? 0 : (1 << (l - 1));
        uint2 x[4];
        float wv[4];
        #pragma unroll
        for (int i = 0; i < 4; ++i) {
            const int cn = (n[i] + off) & (NN - 1);
            x[i] = Vin[base + (size_t)cn * 64];
            wv[i] = wrow[i][l];
        }
        #pragma unroll
        for (int i = 0; i < 4; ++i) {
            float x0, x1, x2, x3;
            unpack2(x[i].x, x0, x1);
            unpack2(x[i].y, x2, x3);
            a[i][0] = __builtin_fmaf(wv[i], x0, a[i][0]);
            a[i][1] = __builtin_fmaf(wv[i], x1, a[i][1]);
            a[i][2] = __builtin_fmaf(wv[i], x2, a[i][2]);
            a[i][3] = __builtin_fmaf(wv[i], x3, a[i][3]);
        }
    }

    #pragma unroll
    for (int i = 0; i < 4; ++i) {
        const int r = r0 + i * 4;
        if constexpr (LAST) {
            float4 o = {a[i][0], a[i][1], a[i][2], a[i][3]};
            ((float4*)Vout)[(size_t)r * 64 + e] = o;
        } else {
            uint2 o;
            o.x = pack_bf16_rh(a[i][0], a[i][1]);
            o.y = pack_bf16_rh(a[i][2], a[i][3]);
            ((uint2*)Vout)[(size_t)r * 64 + e] = o;
        }
    }
}

// ---------------------------------------------------------------------------
extern "C" void kernel_launch(void* const* d_in, const int* in_sizes, int n_in,
                              void* d_out, int out_size, void* d_ws, size_t ws_size,
                              hipStream_t stream)
{
    const float* V      = (const float*)d_in[0];
    const float* input  = (const float*)d_in[1];
    const float* g_W1   = (const float*)d_in[2];
    const float* g_b1   = (const float*)d_in[3];
    const float* g_W2   = (const float*)d_in[4];
    const float* g_b2   = (const float*)d_in[5];
    const float* f_W1   = (const float*)d_in[6];
    const float* f_b1   = (const float*)d_in[7];
    const float* f_W2   = (const float*)d_in[8];
    const float* f_b2   = (const float*)d_in[9];
    float* out = (float*)d_out;

    char* ws = (char*)d_ws;
    size_t o = 0;
    __hip_bfloat16* Vb     = (__hip_bfloat16*)(ws + o); o += (size_t)MM * EE * 2;        // 8 MB
    __hip_bfloat16* Xb     = (__hip_bfloat16*)(ws + o); o += (size_t)MM * EE * 2;        // 8 MB
    __hip_bfloat16* gW1t   = (__hip_bfloat16*)(ws + o); o += (size_t)HH * EE * 2;        // 512 KB
    __hip_bfloat16* gW2t   = (__hip_bfloat16*)(ws + o); o += (size_t)EE * HH * 2;        // 512 KB
    __hip_bfloat16* fW1t   = (__hip_bfloat16*)(ws + o); o += (size_t)NW * HH * EE * 2;   // 6 MB
    _Float16*       W2tA   = (_Float16*)(ws + o);       o += (size_t)NW * 16 * HH * 2;   // 384 KB
    __hip_bfloat16* Whb    = (__hip_bfloat16*)(ws + o); o += (size_t)MM * HH * 2;        // 32 MB (gate only)
    float*          Wall   = (float*)(ws + o);          o += (size_t)MM * NW * 16 * 4;   // 12 MB
    __hip_bfloat16* Vg0    = (__hip_bfloat16*)(ws + o); o += (size_t)MM * EE * 2;        // 8 MB
    __hip_bfloat16* Vg1    = (__hip_bfloat16*)(ws + o); o += (size_t)MM * EE * 2;        // 8 MB

    dim3 blk(256);

    // 0. ALL dtype conversion / weight transposes in one launch
    prep_all<<<12544, blk, 0, stream>>>(V, input, g_W1, g_W2, f_W1, f_W2,
                                        Vb, Xb, gW1t, gW2t, fW1t, W2tA);

    // 1. Gate gemm1: A-in-registers, bf16 output (r14/r16-validated)
    gemm1_areg<<<dim3(MM / 128, HH / 128), blk, 0, stream>>>(Vb, gW1t, g_b1, Whb);
    // 2. Gate gemm2 (K=1024), bf16 MFMA, bf16 out -> Vg0
    gemm_bf16<__hip_bfloat16, false><<<dim3(EE / 128, MM / 128), blk, 0, stream>>>(
        Whb, gW2t, g_b2, Vg0, MM, EE, HH);

    // 3. All 12 levels' link weights in ONE fused launch (r15/r16: 138us)
    f_fused<<<dim3(MM / 128, NW), blk, 0, stream>>>(Xb, fW1t, f_b1, W2tA, f_b2, Wall);

    // 4. 12 sequential chord steps, stream-ordered; final widens to f32 out
    const __hip_bfloat16* cur = Vg0;
    __hip_bfloat16* nxt = Vg1;
    for (int m = 0; m < NW - 1; ++m) {
        chord_bf16<false><<<MM / 16, blk, 0, stream>>>(
            (const uint2*)cur, Wall, nxt, m);
        __hip_bfloat16* tswap = (__hip_bfloat16*)cur;
        cur = nxt;
        nxt = tswap;
    }
    chord_bf16<true><<<MM / 16, blk, 0, stream>>>(
        (const uint2*)cur, Wall, out, NW - 1);
}

// Round 19
// 278.039 us; speedup vs baseline: 1.1850x; 1.1821x over previous
//
#include <hip/hip_runtime.h>
#include <hip/hip_bf16.h>
#include <hip/hip_fp16.h>
#include <math.h>

// Problem constants
#define BB 4
#define NN 4096
#define EE 256
#define HH 1024
#define NW 12
#define NL 13
#define MM (BB * NN)   // 16384 rows

typedef __attribute__((ext_vector_type(8))) short short8;   // 8x16b (4 VGPRs)
typedef __attribute__((ext_vector_type(4))) float f32x4;
typedef __attribute__((ext_vector_type(2))) _Float16 h2;    // packed f16 pair
typedef __attribute__((ext_vector_type(8))) _Float16 half8; // f16 MFMA frag

// Fast gelu, f32 scalar: x*sigmoid(1.5957691(x+0.044715x^3)), exp2 form.
__device__ __forceinline__ float gelu_fast(float x) {
    float t = __builtin_fmaf(0.044715f, x * x, 1.0f);
    float e = __builtin_amdgcn_exp2f(-2.3021193f * (x * t));
    return x * __builtin_amdgcn_rcpf(1.0f + e);
}

// Packed-f16 gelu on a pair of f32 inputs -> packed f16 pair bits (r15: -7us).
__device__ __forceinline__ unsigned gelu2_f16(float a, float b) {
    const h2 C1 = {(_Float16)-2.3021193f, (_Float16)-2.3021193f};
    const h2 C2 = {(_Float16)0.044715f, (_Float16)0.044715f};
    const h2 ONE = {(_Float16)1.0f, (_Float16)1.0f};
    h2 x;
    asm("v_cvt_pkrtz_f16_f32 %0, %1, %2" : "=v"(x) : "v"(a), "v"(b));
    h2 x2 = x * x;
    h2 t  = C2 * x2 + ONE;          // v_pk_fma_f16
    h2 z  = (C1 * x) * t;
    __half2 es = h2exp2(__builtin_bit_cast(__half2, z));
    h2 d = ONE + __builtin_bit_cast(h2, es);
    __half2 rs = h2rcp(__builtin_bit_cast(__half2, d));
    h2 y = x * __builtin_bit_cast(h2, rs);
    return __builtin_bit_cast(unsigned, y);
}

// Arithmetic bf16 pack (r14-validated in chord).
__device__ __forceinline__ unsigned pack_bf16_rh(float a, float b) {
    unsigned ua = (__builtin_bit_cast(unsigned, a) + 0x8000u) >> 16;
    unsigned ub = (__builtin_bit_cast(unsigned, b) + 0x8000u) & 0xFFFF0000u;
    return ua | ub;
}

// HW packed f32->2xbf16 (RNE), 1 VALU op.
__device__ __forceinline__ unsigned cvt_pk_bf16(float a, float b) {
    unsigned r;
    asm("v_cvt_pk_bf16_f32 %0, %1, %2" : "=v"(r) : "v"(a), "v"(b));
    return r;
}

__device__ __forceinline__ void unpack2(unsigned u, float& lo, float& hi) {
    lo = __builtin_bit_cast(float, u << 16);
    hi = __builtin_bit_cast(float, u & 0xFFFF0000u);
}

__device__ __forceinline__ void load_lds16(const void* g, void* l) {
    __builtin_amdgcn_global_load_lds(
        (const __attribute__((address_space(1))) void*)g,
        (__attribute__((address_space(3))) void*)l, 16, 0, 0);
}

// ---------------------------------------------------------------------------
// bf16 MFMA GEMM (m97 structure). Used for gate gemm2 (K=1024).
// ---------------------------------------------------------------------------
template<typename OutT, bool GELU>
__global__ __launch_bounds__(256) void gemm_bf16(
    const __hip_bfloat16* __restrict__ A,   // M x K  row-major
    const __hip_bfloat16* __restrict__ Bt,  // N x K  row-major (pre-transposed)
    const float* __restrict__ bias,         // N
    OutT* __restrict__ C,                   // M x N
    int M, int N, int K)
{
    __shared__ __hip_bfloat16 As[128 * 32];
    __shared__ __hip_bfloat16 Bs[128 * 32];

    const int tid = threadIdx.x;
    const int w = tid >> 6, l = tid & 63;
    const int wr = w >> 1, wc = w & 1;       // 2x2 wave grid, each 64x64
    const int row0 = blockIdx.y * 128;
    const int col0 = blockIdx.x * 128;

    const int c0 = w * 64 + l;
    const int c1 = c0 + 256;
    const __hip_bfloat16* gA0 = A  + (size_t)(row0 + (c0 >> 2)) * K + (c0 & 3) * 8;
    const __hip_bfloat16* gA1 = A  + (size_t)(row0 + (c1 >> 2)) * K + (c1 & 3) * 8;
    const __hip_bfloat16* gB0 = Bt + (size_t)(col0 + (c0 >> 2)) * K + (c0 & 3) * 8;
    const __hip_bfloat16* gB1 = Bt + (size_t)(col0 + (c1 >> 2)) * K + (c1 & 3) * 8;
    char* dA0 = (char*)As + w * 1024;
    char* dA1 = (char*)As + w * 1024 + 4096;
    char* dB0 = (char*)Bs + w * 1024;
    char* dB1 = (char*)Bs + w * 1024 + 4096;

    const int lr = l & 15;
    const int lk = (l >> 4) * 8;

    f32x4 acc[4][4] = {};

    for (int k0 = 0; k0 < K; k0 += 32) {
        load_lds16(gA0 + k0, dA0);
        load_lds16(gA1 + k0, dA1);
        load_lds16(gB0 + k0, dB0);
        load_lds16(gB1 + k0, dB1);
        __syncthreads();

        short8 a[4], b[4];
        #pragma unroll
        for (int m = 0; m < 4; ++m)
            a[m] = *(const short8*)&As[(wr * 64 + m * 16 + lr) * 32 + lk];
        #pragma unroll
        for (int n = 0; n < 4; ++n)
            b[n] = *(const short8*)&Bs[(wc * 64 + n * 16 + lr) * 32 + lk];
        #pragma unroll
        for (int m = 0; m < 4; ++m)
            #pragma unroll
            for (int n = 0; n < 4; ++n)
                acc[m][n] = __builtin_amdgcn_mfma_f32_16x16x32_bf16(a[m], b[n], acc[m][n], 0, 0, 0);
        __syncthreads();
    }

    #pragma unroll
    for (int m = 0; m < 4; ++m) {
        #pragma unroll
        for (int n = 0; n < 4; ++n) {
            const int col = col0 + wc * 64 + n * 16 + lr;
            const float bv = bias[col];
            #pragma unroll
            for (int j = 0; j < 4; ++j) {
                const int row = row0 + wr * 64 + m * 16 + (l >> 4) * 4 + j;
                float v = acc[m][n][j] + bv;
                if (GELU) v = gelu_fast(v);
                if constexpr (sizeof(OutT) == 2)
                    C[(size_t)row * N + col] = __float2bfloat16(v);
                else
                    C[(size_t)row * N + col] = v;
            }
        }
    }
}

// ---------------------------------------------------------------------------
// Gate gemm1, A-in-registers (r14/r16-validated): Wh(bf16) = gelu(Vb@W1+b1).
// ---------------------------------------------------------------------------
__global__ __launch_bounds__(256, 3) void gemm1_areg(
    const __hip_bfloat16* __restrict__ A,     // MM x EE (Vb)
    const __hip_bfloat16* __restrict__ W1t,   // HH x EE
    const float* __restrict__ b1,             // HH
    __hip_bfloat16* __restrict__ Wh)          // MM x HH
{
    __shared__ __hip_bfloat16 Bs[8 * 64 * 32];   // 32 KB [kk][row][32]
    __shared__ __align__(16) char Gb[4][4096];   // per-wave G [32r][64h]

    const int tid = threadIdx.x;
    const int w = tid >> 6, l = tid & 63;
    const int row0 = blockIdx.x * 128;
    const int col0 = blockIdx.y * 128;
    const int lr = l & 15, g = l >> 4, lk = g * 8;

    short8 xf[2][8];
    {
        const __hip_bfloat16* xp0 = A + (size_t)(row0 + w * 32 + lr) * EE + lk;
        #pragma unroll
        for (int kk = 0; kk < 8; ++kk) {
            xf[0][kk] = *(const short8*)(xp0 + kk * 32);
            xf[1][kk] = *(const short8*)(xp0 + 16 * EE + kk * 32);
        }
    }
    char* Gw = Gb[w];

    #pragma unroll
    for (int rstep = 0; rstep < 8; ++rstep) {
        const int c = rstep * 256 + tid;
        load_lds16(W1t + (size_t)(col0 + ((c >> 2) & 63)) * EE + (c >> 8) * 32 + (c & 3) * 8,
                   (char*)Bs + c * 16);
    }
    __syncthreads();

    #pragma unroll 1
    for (int ct = 0; ct < 2; ++ct) {
        f32x4 acc[4][2];
        #pragma unroll
        for (int ni = 0; ni < 4; ++ni) {
            const float4 bv = *(const float4*)&b1[col0 + ct * 64 + ni * 16 + g * 4];
            const f32x4 bi = {bv.x, bv.y, bv.z, bv.w};
            acc[ni][0] = bi;
            acc[ni][1] = bi;
        }
        __builtin_amdgcn_s_setprio(1);
        #pragma unroll
        for (int kk = 0; kk < 8; ++kk) {
            short8 a[4];
            #pragma unroll
            for (int ni = 0; ni < 4; ++ni)
                a[ni] = *(const short8*)((const char*)Bs +
                         (kk * 4096 + ni * 1024 + lr * 64 + g * 16));
            #pragma unroll
            for (int ni = 0; ni < 4; ++ni) {
                acc[ni][0] = __builtin_amdgcn_mfma_f32_16x16x32_bf16(a[ni], xf[0][kk], acc[ni][0], 0, 0, 0);
                acc[ni][1] = __builtin_amdgcn_mfma_f32_16x16x32_bf16(a[ni], xf[1][kk], acc[ni][1], 0, 0, 0);
            }
        }
        __builtin_amdgcn_s_setprio(0);
        __syncthreads();

        if (ct == 0) {
            #pragma unroll
            for (int rstep = 0; rstep < 8; ++rstep) {
                const int c = rstep * 256 + tid;
                load_lds16(W1t + (size_t)(col0 + 64 + ((c >> 2) & 63)) * EE + (c >> 8) * 32 + (c & 3) * 8,
                           (char*)Bs + c * 16);
            }
        }

        // gelu (f32) -> bf16 (cvt_pk) -> wave-private swizzled G
        #pragma unroll
        for (int ni = 0; ni < 4; ++ni) {
            #pragma unroll
            for (int mi = 0; mi < 2; ++mi) {
                const int rloc = mi * 16 + lr;
                const float v0 = gelu_fast(acc[ni][mi][0]);
                const float v1 = gelu_fast(acc[ni][mi][1]);
                const float v2 = gelu_fast(acc[ni][mi][2]);
                const float v3 = gelu_fast(acc[ni][mi][3]);
                uint2 pk;
                pk.x = cvt_pk_bf16(v0, v1);
                pk.y = cvt_pk_bf16(v2, v3);
                const int byte = (rloc * 128 + (ni * 16 + g * 4) * 2) ^ ((rloc & 7) << 4);
                *(uint2*)(Gw + byte) = pk;
            }
        }

        // coalesced store: 4 passes x (8 rows x 128B); G is wave-private
        #pragma unroll
        for (int p = 0; p < 4; ++p) {
            const int rl = p * 8 + (l >> 3);
            const int hb = (l & 7) * 16;
            const uint4 v = *(const uint4*)(Gw + ((rl * 128 + hb) ^ ((rl & 7) << 4)));
            *(uint4*)((char*)(Wh + (size_t)(row0 + w * 32 + rl) * HH + col0 + ct * 64) + hb) = v;
        }
        __syncthreads();
    }
}

// ---------------------------------------------------------------------------
// Fused f-level kernel (r15/r16-validated 138 us), epilogue now writes
// Wall TRANSPOSED: Wall_t[(m*16 + l)][MM] so the chord kernel's per-lane
// weight loads are coalesced.
// ---------------------------------------------------------------------------
__global__ __launch_bounds__(256, 3) void f_fused(
    const __hip_bfloat16* __restrict__ X,     // MM x EE (bf16)
    const __hip_bfloat16* __restrict__ W1t,   // NW x HH x EE (bf16)
    const float* __restrict__ b1,             // NW x HH
    const _Float16* __restrict__ W2t,         // NW x 16 x HH (f16)
    const float* __restrict__ b2,             // NW x NL
    float* __restrict__ Wall_t)               // [NW*16][MM]
{
    __shared__ __hip_bfloat16 Bs[8 * 64 * 32];        // 32 KB [kk][row][32]
    __shared__ __align__(16) char Gb[4][4096];        // per-wave G [32r][64h] f16
    __shared__ float biasS[HH];                       // 4 KB

    const int tid = threadIdx.x;
    const int w = tid >> 6, l = tid & 63;
    const int row0 = blockIdx.x * 128;
    const int m_lv = blockIdx.y;
    const int lr = l & 15;
    const int g  = l >> 4;
    const int lk = g * 8;

    const __hip_bfloat16* W1m = W1t + (size_t)m_lv * HH * EE;

    ((float4*)biasS)[tid] = ((const float4*)(b1 + (size_t)m_lv * HH))[tid];

    short8 xf[2][8];
    {
        const __hip_bfloat16* xp0 = X + (size_t)(row0 + w * 32 + lr) * EE + lk;
        #pragma unroll
        for (int kk = 0; kk < 8; ++kk) {
            xf[0][kk] = *(const short8*)(xp0 + kk * 32);
            xf[1][kk] = *(const short8*)(xp0 + 16 * EE + kk * 32);
        }
    }

    const _Float16* w2p = W2t + ((size_t)m_lv * 16 + lr) * HH + lk;
    char* Gw = Gb[w];

    f32x4 wacc0 = {}, wacc1 = {};

    #pragma unroll
    for (int rstep = 0; rstep < 8; ++rstep) {
        const int c = rstep * 256 + tid;
        load_lds16(W1m + (size_t)((c >> 2) & 63) * EE + (c >> 8) * 32 + (c & 3) * 8,
                   (char*)Bs + c * 16);
    }
    __syncthreads();

    #pragma unroll 1
    for (int ct = 0; ct < 16; ++ct) {
        // acc C-in = bias
        f32x4 acc[4][2];
        #pragma unroll
        for (int ni = 0; ni < 4; ++ni) {
            const float4 bv = *(const float4*)&biasS[ct * 64 + ni * 16 + g * 4];
            const f32x4 bi = {bv.x, bv.y, bv.z, bv.w};
            acc[ni][0] = bi;
            acc[ni][1] = bi;
        }
        __builtin_amdgcn_s_setprio(1);
        #pragma unroll
        for (int kk = 0; kk < 8; ++kk) {
            short8 a[4];
            #pragma unroll
            for (int ni = 0; ni < 4; ++ni)
                a[ni] = *(const short8*)((const char*)Bs +
                         (kk * 4096 + ni * 1024 + lr * 64 + g * 16));
            #pragma unroll
            for (int ni = 0; ni < 4; ++ni) {
                acc[ni][0] = __builtin_amdgcn_mfma_f32_16x16x32_bf16(a[ni], xf[0][kk], acc[ni][0], 0, 0, 0);
                acc[ni][1] = __builtin_amdgcn_mfma_f32_16x16x32_bf16(a[ni], xf[1][kk], acc[ni][1], 0, 0, 0);
            }
        }
        __builtin_amdgcn_s_setprio(0);
        __syncthreads();                       // all waves done reading Bs

        if (ct < 15) {
            const __hip_bfloat16* W1n = W1m + (size_t)(ct + 1) * 64 * EE;
            #pragma unroll
            for (int rstep = 0; rstep < 8; ++rstep) {
                const int c = rstep * 256 + tid;
                load_lds16(W1n + (size_t)((c >> 2) & 63) * EE + (c >> 8) * 32 + (c & 3) * 8,
                           (char*)Bs + c * 16);
            }
        }

        // gelu (packed f16) -> wave-private swizzled G (f16)
        #pragma unroll
        for (int ni = 0; ni < 4; ++ni) {
            #pragma unroll
            for (int mi = 0; mi < 2; ++mi) {
                const int rloc = mi * 16 + lr;
                uint2 pk;
                pk.x = gelu2_f16(acc[ni][mi][0], acc[ni][mi][1]);
                pk.y = gelu2_f16(acc[ni][mi][2], acc[ni][mi][3]);
                const int byte = (rloc * 128 + (ni * 16 + g * 4) * 2) ^ ((rloc & 7) << 4);
                *(uint2*)(Gw + byte) = pk;
            }
        }

        // mini-GEMM (f16): Wall-frag += W2t[ct k-range] x G
        #pragma unroll
        for (int ks2 = 0; ks2 < 2; ++ks2) {
            const half8 aw = *(const half8*)(w2p + ct * 64 + ks2 * 32);
            {
                const int byte = (lr * 128 + (ks2 * 32 + lk) * 2) ^ ((lr & 7) << 4);
                const half8 bg = *(const half8*)(Gw + byte);
                wacc0 = __builtin_amdgcn_mfma_f32_16x16x32_f16(aw, bg, wacc0, 0, 0, 0);
            }
            {
                const int rloc = 16 + lr;
                const int byte = (rloc * 128 + (ks2 * 32 + lk) * 2) ^ ((rloc & 7) << 4);
                const half8 bg = *(const half8*)(Gw + byte);
                wacc1 = __builtin_amdgcn_mfma_f32_16x16x32_f16(aw, bg, wacc1, 0, 0, 0);
            }
        }
        __syncthreads();                       // staging drained; Bs ready
    }

    // epilogue -> Wall_t[(m*16 + lval)*MM + r]
    const float* b2m = b2 + m_lv * NL;
    #pragma unroll
    for (int j = 0; j < 4; ++j) {
        const int lval = g * 4 + j;
        const float bv = (lval < NL) ? b2m[lval] : 0.f;
        float* wp = Wall_t + (size_t)(m_lv * 16 + lval) * MM;
        wp[row0 + w * 32 + lr]      = wacc0[j] + bv;
        wp[row0 + w * 32 + 16 + lr] = wacc1[j] + bv;
    }
}

// ---------------------------------------------------------------------------
// One prep kernel for ALL conversions/transposes.
// ---------------------------------------------------------------------------
struct bf4 { __hip_bfloat16 a, b, c, d; };

__device__ __forceinline__ void cvt_body(
    const float* __restrict__ in, __hip_bfloat16* __restrict__ out, int i)
{
    float4 v = ((const float4*)in)[i];
    bf4 o;
    o.a = __float2bfloat16(v.x); o.b = __float2bfloat16(v.y);
    o.c = __float2bfloat16(v.z); o.d = __float2bfloat16(v.w);
    ((bf4*)out)[i] = o;
}

__device__ __forceinline__ void transpose_body(
    const float* __restrict__ inB, __hip_bfloat16* __restrict__ outB,
    int K, int N, int bx, int by, float (*t)[33])
{
    const int n0 = bx * 32, k0 = by * 32;
    const int tx = threadIdx.x & 31, ty = threadIdx.x >> 5;  // 32 x 8
    #pragma unroll
    for (int i = 0; i < 32; i += 8)
        t[ty + i][tx] = inB[(size_t)(k0 + ty + i) * N + n0 + tx];
    __syncthreads();
    #pragma unroll
    for (int i = 0; i < 32; i += 8)
        outB[(size_t)(n0 + ty + i) * K + k0 + tx] = __float2bfloat16(t[tx][ty + i]);
}

__global__ __launch_bounds__(256) void prep_all(
    const float* __restrict__ V, const float* __restrict__ input,
    const float* __restrict__ g_W1, const float* __restrict__ g_W2,
    const float* __restrict__ f_W1, const float* __restrict__ f_W2,
    __hip_bfloat16* __restrict__ Vb, __hip_bfloat16* __restrict__ Xb,
    __hip_bfloat16* __restrict__ gW1t, __hip_bfloat16* __restrict__ gW2t,
    __hip_bfloat16* __restrict__ fW1t, _Float16* __restrict__ W2tA)
{
    __shared__ float t[32][33];
    const int bid = blockIdx.x;
    const int tid = threadIdx.x;

    if (bid < 4096) {
        cvt_body(V, Vb, bid * 256 + tid);
    } else if (bid < 8192) {
        cvt_body(input, Xb, (bid - 4096) * 256 + tid);
    } else if (bid < 8448) {
        const int b2 = bid - 8192;                   // g_W1: grid (32, 8)
        transpose_body(g_W1, gW1t, EE, HH, b2 & 31, b2 >> 5, t);
    } else if (bid < 8704) {
        const int b2 = bid - 8448;                   // g_W2: grid (8, 32)
        transpose_body(g_W2, gW2t, HH, EE, b2 & 7, b2 >> 3, t);
    } else if (bid < 11776) {
        const int b2 = bid - 8704;                   // f_W1: 12 x (32, 8)
        const int z = b2 >> 8, r = b2 & 255;
        transpose_body(f_W1 + (size_t)z * EE * HH, fW1t + (size_t)z * HH * EE,
                       EE, HH, r & 31, r >> 5, t);
    } else {
        const int idx = (bid - 11776) * 256 + tid;   // w2t: NW*16*HH elems, f16
        const int m = idx >> 14;
        const int n = (idx >> 10) & 15;
        const int h = idx & 1023;
        const float v = (n < NL) ? f_W2[((size_t)m * HH + h) * NL + n] : 0.f;
        W2tA[idx] = (_Float16)v;
    }
}

// ---------------------------------------------------------------------------
// ALL 12 chord steps in ONE kernel, state resident in LDS.
// Chord mixing is channel-independent: block = (batch, 4-channel slice).
// State = 4096 rows x 4 ch bf16 = 32 KB, double-buffered (64 KB LDS).
// 256 blocks x 512 threads (8 waves, 2/SIMD); thread owns 8 rows.
// Steps separated by __syncthreads() only -- no HBM state round-trips,
// no per-step launches. Weights read coalesced from Wall_t[(m*16+l)][MM].
// ---------------------------------------------------------------------------
__global__ __launch_bounds__(512, 1) void chord_lds(
    const uint2* __restrict__ Vg,     // MM x 64 (4 bf16 per slot) initial state
    const float* __restrict__ Wall_t, // [NW*16][MM]
    float4* __restrict__ outF)        // MM x 64 (f32 x4) final output
{
    __shared__ unsigned L[2][2][NN];   // [buf][ch-pair][row]  64 KB

    const int tid = threadIdx.x;       // 0..511
    const int bid = blockIdx.x;        // 0..255
    const int batch = bid >> 6;
    const int slice = bid & 63;        // 4-channel slice
    const int gbase = batch * NN;

    // init: load own 8 rows from global (bf16 x4 per row)
    #pragma unroll
    for (int i = 0; i < 8; ++i) {
        const int n = tid + i * 512;
        const uint2 u = Vg[(size_t)(gbase + n) * 64 + slice];
        L[0][0][n] = u.x;
        L[0][1][n] = u.y;
    }
    __syncthreads();

    int cur = 0;
    #pragma unroll 1
    for (int m = 0; m < NW; ++m) {
        const float* wbase = Wall_t + (size_t)m * 16 * MM + gbase;
        const int nxt = cur ^ 1;
        #pragma unroll 1
        for (int i = 0; i < 8; ++i) {
            const int n = tid + i * 512;
            float a0, a1, a2, a3;
            unpack2(L[cur][0][n], a0, a1);
            unpack2(L[cur][1][n], a2, a3);
            #pragma unroll
            for (int l = 0; l < NL; ++l) {
                const int off = (l == 0) ? 0 : (1 << (l - 1));
                const int cn = (n + off) & (NN - 1);
                const float wv = wbase[(size_t)l * MM + n];
                float x0, x1, x2, x3;
                unpack2(L[cur][0][cn], x0, x1);
                unpack2(L[cur][1][cn], x2, x3);
                a0 = __builtin_fmaf(wv, x0, a0);
                a1 = __builtin_fmaf(wv, x1, a1);
                a2 = __builtin_fmaf(wv, x2, a2);
                a3 = __builtin_fmaf(wv, x3, a3);
            }
            if (m == NW - 1) {
                float4 o = {a0, a1, a2, a3};
                outF[(size_t)(gbase + n) * 64 + slice] = o;
            } else {
                L[nxt][0][n] = pack_bf16_rh(a0, a1);
                L[nxt][1][n] = pack_bf16_rh(a2, a3);
            }
        }
        __syncthreads();
        cur ^= 1;
    }
}

// ---------------------------------------------------------------------------
extern "C" void kernel_launch(void* const* d_in, const int* in_sizes, int n_in,
                              void* d_out, int out_size, void* d_ws, size_t ws_size,
                              hipStream_t stream)
{
    const float* V      = (const float*)d_in[0];
    const float* input  = (const float*)d_in[1];
    const float* g_W1   = (const float*)d_in[2];
    const float* g_b1   = (const float*)d_in[3];
    const float* g_W2   = (const float*)d_in[4];
    const float* g_b2   = (const float*)d_in[5];
    const float* f_W1   = (const float*)d_in[6];
    const float* f_b1   = (const float*)d_in[7];
    const float* f_W2   = (const float*)d_in[8];
    const float* f_b2   = (const float*)d_in[9];
    float* out = (float*)d_out;

    char* ws = (char*)d_ws;
    size_t o = 0;
    __hip_bfloat16* Vb     = (__hip_bfloat16*)(ws + o); o += (size_t)MM * EE * 2;        // 8 MB
    __hip_bfloat16* Xb     = (__hip_bfloat16*)(ws + o); o += (size_t)MM * EE * 2;        // 8 MB
    __hip_bfloat16* gW1t   = (__hip_bfloat16*)(ws + o); o += (size_t)HH * EE * 2;        // 512 KB
    __hip_bfloat16* gW2t   = (__hip_bfloat16*)(ws + o); o += (size_t)EE * HH * 2;        // 512 KB
    __hip_bfloat16* fW1t   = (__hip_bfloat16*)(ws + o); o += (size_t)NW * HH * EE * 2;   // 6 MB
    _Float16*       W2tA   = (_Float16*)(ws + o);       o += (size_t)NW * 16 * HH * 2;   // 384 KB
    __hip_bfloat16* Whb    = (__hip_bfloat16*)(ws + o); o += (size_t)MM * HH * 2;        // 32 MB (gate only)
    float*          Wall   = (float*)(ws + o);          o += (size_t)NW * 16 * MM * 4;   // 12 MB (transposed)
    __hip_bfloat16* Vg0    = (__hip_bfloat16*)(ws + o); o += (size_t)MM * EE * 2;        // 8 MB

    dim3 blk(256);

    // 0. ALL dtype conversion / weight transposes in one launch
    prep_all<<<12544, blk, 0, stream>>>(V, input, g_W1, g_W2, f_W1, f_W2,
                                        Vb, Xb, gW1t, gW2t, fW1t, W2tA);

    // 1. Gate gemm1: A-in-registers, bf16 output (r14/r16-validated)
    gemm1_areg<<<dim3(MM / 128, HH / 128), blk, 0, stream>>>(Vb, gW1t, g_b1, Whb);
    // 2. Gate gemm2 (K=1024), bf16 MFMA, bf16 out -> Vg0
    gemm_bf16<__hip_bfloat16, false><<<dim3(EE / 128, MM / 128), blk, 0, stream>>>(
        Whb, gW2t, g_b2, Vg0, MM, EE, HH);

    // 3. All 12 levels' link weights in ONE fused launch (Wall transposed)
    f_fused<<<dim3(MM / 128, NW), blk, 0, stream>>>(Xb, fW1t, f_b1, W2tA, f_b2, Wall);

    // 4. ALL 12 chord steps in ONE launch, LDS-resident state
    chord_lds<<<256, dim3(512), 0, stream>>>((const uint2*)Vg0, Wall, (float4*)out);
}

// Round 20
// 264.111 us; speedup vs baseline: 1.2475x; 1.0527x over previous
//
#include <hip/hip_runtime.h>
#include <hip/hip_bf16.h>
#include <hip/hip_fp16.h>
#include <math.h>

// Problem constants
#define BB 4
#define NN 4096
#define EE 256
#define HH 1024
#define NW 12
#define NL 13
#define MM (BB * NN)   // 16384 rows

typedef __attribute__((ext_vector_type(8))) short short8;   // 8x16b (4 VGPRs)
typedef __attribute__((ext_vector_type(4))) float f32x4;
typedef __attribute__((ext_vector_type(2))) _Float16 h2;    // packed f16 pair
typedef __attribute__((ext_vector_type(8))) _Float16 half8; // f16 MFMA frag

// Fast gelu, f32 scalar: x*sigmoid(1.5957691(x+0.044715x^3)), exp2 form.
__device__ __forceinline__ float gelu_fast(float x) {
    float t = __builtin_fmaf(0.044715f, x * x, 1.0f);
    float e = __builtin_amdgcn_exp2f(-2.3021193f * (x * t));
    return x * __builtin_amdgcn_rcpf(1.0f + e);
}

// Packed-f16 gelu on a pair of f32 inputs -> packed f16 pair bits (r15: -7us).
__device__ __forceinline__ unsigned gelu2_f16(float a, float b) {
    const h2 C1 = {(_Float16)-2.3021193f, (_Float16)-2.3021193f};
    const h2 C2 = {(_Float16)0.044715f, (_Float16)0.044715f};
    const h2 ONE = {(_Float16)1.0f, (_Float16)1.0f};
    h2 x;
    asm("v_cvt_pkrtz_f16_f32 %0, %1, %2" : "=v"(x) : "v"(a), "v"(b));
    h2 x2 = x * x;
    h2 t  = C2 * x2 + ONE;          // v_pk_fma_f16
    h2 z  = (C1 * x) * t;
    __half2 es = h2exp2(__builtin_bit_cast(__half2, z));
    h2 d = ONE + __builtin_bit_cast(h2, es);
    __half2 rs = h2rcp(__builtin_bit_cast(__half2, d));
    h2 y = x * __builtin_bit_cast(h2, rs);
    return __builtin_bit_cast(unsigned, y);
}

// Arithmetic bf16 pack (r14-validated in chord).
__device__ __forceinline__ unsigned pack_bf16_rh(float a, float b) {
    unsigned ua = (__builtin_bit_cast(unsigned, a) + 0x8000u) >> 16;
    unsigned ub = (__builtin_bit_cast(unsigned, b) + 0x8000u) & 0xFFFF0000u;
    return ua | ub;
}

// HW packed f32->2xbf16 (RNE), 1 VALU op.
__device__ __forceinline__ unsigned cvt_pk_bf16(float a, float b) {
    unsigned r;
    asm("v_cvt_pk_bf16_f32 %0, %1, %2" : "=v"(r) : "v"(a), "v"(b));
    return r;
}

__device__ __forceinline__ void unpack2(unsigned u, float& lo, float& hi) {
    lo = __builtin_bit_cast(float, u << 16);
    hi = __builtin_bit_cast(float, u & 0xFFFF0000u);
}

__device__ __forceinline__ void load_lds16(const void* g, void* l) {
    __builtin_amdgcn_global_load_lds(
        (const __attribute__((address_space(1))) void*)g,
        (__attribute__((address_space(3))) void*)l, 16, 0, 0);
}

// ---------------------------------------------------------------------------
// bf16 MFMA GEMM (m97 structure). Used for gate gemm2 (K=1024).
// ---------------------------------------------------------------------------
template<typename OutT, bool GELU>
__global__ __launch_bounds__(256) void gemm_bf16(
    const __hip_bfloat16* __restrict__ A,   // M x K  row-major
    const __hip_bfloat16* __restrict__ Bt,  // N x K  row-major (pre-transposed)
    const float* __restrict__ bias,         // N
    OutT* __restrict__ C,                   // M x N
    int M, int N, int K)
{
    __shared__ __hip_bfloat16 As[128 * 32];
    __shared__ __hip_bfloat16 Bs[128 * 32];

    const int tid = threadIdx.x;
    const int w = tid >> 6, l = tid & 63;
    const int wr = w >> 1, wc = w & 1;       // 2x2 wave grid, each 64x64
    const int row0 = blockIdx.y * 128;
    const int col0 = blockIdx.x * 128;

    const int c0 = w * 64 + l;
    const int c1 = c0 + 256;
    const __hip_bfloat16* gA0 = A  + (size_t)(row0 + (c0 >> 2)) * K + (c0 & 3) * 8;
    const __hip_bfloat16* gA1 = A  + (size_t)(row0 + (c1 >> 2)) * K + (c1 & 3) * 8;
    const __hip_bfloat16* gB0 = Bt + (size_t)(col0 + (c0 >> 2)) * K + (c0 & 3) * 8;
    const __hip_bfloat16* gB1 = Bt + (size_t)(col0 + (c1 >> 2)) * K + (c1 & 3) * 8;
    char* dA0 = (char*)As + w * 1024;
    char* dA1 = (char*)As + w * 1024 + 4096;
    char* dB0 = (char*)Bs + w * 1024;
    char* dB1 = (char*)Bs + w * 1024 + 4096;

    const int lr = l & 15;
    const int lk = (l >> 4) * 8;

    f32x4 acc[4][4] = {};

    for (int k0 = 0; k0 < K; k0 += 32) {
        load_lds16(gA0 + k0, dA0);
        load_lds16(gA1 + k0, dA1);
        load_lds16(gB0 + k0, dB0);
        load_lds16(gB1 + k0, dB1);
        __syncthreads();

        short8 a[4], b[4];
        #pragma unroll
        for (int m = 0; m < 4; ++m)
            a[m] = *(const short8*)&As[(wr * 64 + m * 16 + lr) * 32 + lk];
        #pragma unroll
        for (int n = 0; n < 4; ++n)
            b[n] = *(const short8*)&Bs[(wc * 64 + n * 16 + lr) * 32 + lk];
        #pragma unroll
        for (int m = 0; m < 4; ++m)
            #pragma unroll
            for (int n = 0; n < 4; ++n)
                acc[m][n] = __builtin_amdgcn_mfma_f32_16x16x32_bf16(a[m], b[n], acc[m][n], 0, 0, 0);
        __syncthreads();
    }

    #pragma unroll
    for (int m = 0; m < 4; ++m) {
        #pragma unroll
        for (int n = 0; n < 4; ++n) {
            const int col = col0 + wc * 64 + n * 16 + lr;
            const float bv = bias[col];
            #pragma unroll
            for (int j = 0; j < 4; ++j) {
                const int row = row0 + wr * 64 + m * 16 + (l >> 4) * 4 + j;
                float v = acc[m][n][j] + bv;
                if (GELU) v = gelu_fast(v);
                if constexpr (sizeof(OutT) == 2)
                    C[(size_t)row * N + col] = __float2bfloat16(v);
                else
                    C[(size_t)row * N + col] = v;
            }
        }
    }
}

// ---------------------------------------------------------------------------
// Gate gemm1, A-in-registers (r14/r16-validated): Wh(bf16) = gelu(Vb@W1+b1).
// ---------------------------------------------------------------------------
__global__ __launch_bounds__(256, 3) void gemm1_areg(
    const __hip_bfloat16* __restrict__ A,     // MM x EE (Vb)
    const __hip_bfloat16* __restrict__ W1t,   // HH x EE
    const float* __restrict__ b1,             // HH
    __hip_bfloat16* __restrict__ Wh)          // MM x HH
{
    __shared__ __hip_bfloat16 Bs[8 * 64 * 32];   // 32 KB [kk][row][32]
    __shared__ __align__(16) char Gb[4][4096];   // per-wave G [32r][64h]

    const int tid = threadIdx.x;
    const int w = tid >> 6, l = tid & 63;
    const int row0 = blockIdx.x * 128;
    const int col0 = blockIdx.y * 128;
    const int lr = l & 15, g = l >> 4, lk = g * 8;

    short8 xf[2][8];
    {
        const __hip_bfloat16* xp0 = A + (size_t)(row0 + w * 32 + lr) * EE + lk;
        #pragma unroll
        for (int kk = 0; kk < 8; ++kk) {
            xf[0][kk] = *(const short8*)(xp0 + kk * 32);
            xf[1][kk] = *(const short8*)(xp0 + 16 * EE + kk * 32);
        }
    }
    char* Gw = Gb[w];

    #pragma unroll
    for (int rstep = 0; rstep < 8; ++rstep) {
        const int c = rstep * 256 + tid;
        load_lds16(W1t + (size_t)(col0 + ((c >> 2) & 63)) * EE + (c >> 8) * 32 + (c & 3) * 8,
                   (char*)Bs + c * 16);
    }
    __syncthreads();

    #pragma unroll 1
    for (int ct = 0; ct < 2; ++ct) {
        f32x4 acc[4][2];
        #pragma unroll
        for (int ni = 0; ni < 4; ++ni) {
            const float4 bv = *(const float4*)&b1[col0 + ct * 64 + ni * 16 + g * 4];
            const f32x4 bi = {bv.x, bv.y, bv.z, bv.w};
            acc[ni][0] = bi;
            acc[ni][1] = bi;
        }
        __builtin_amdgcn_s_setprio(1);
        #pragma unroll
        for (int kk = 0; kk < 8; ++kk) {
            short8 a[4];
            #pragma unroll
            for (int ni = 0; ni < 4; ++ni)
                a[ni] = *(const short8*)((const char*)Bs +
                         (kk * 4096 + ni * 1024 + lr * 64 + g * 16));
            #pragma unroll
            for (int ni = 0; ni < 4; ++ni) {
                acc[ni][0] = __builtin_amdgcn_mfma_f32_16x16x32_bf16(a[ni], xf[0][kk], acc[ni][0], 0, 0, 0);
                acc[ni][1] = __builtin_amdgcn_mfma_f32_16x16x32_bf16(a[ni], xf[1][kk], acc[ni][1], 0, 0, 0);
            }
        }
        __builtin_amdgcn_s_setprio(0);
        __syncthreads();

        if (ct == 0) {
            #pragma unroll
            for (int rstep = 0; rstep < 8; ++rstep) {
                const int c = rstep * 256 + tid;
                load_lds16(W1t + (size_t)(col0 + 64 + ((c >> 2) & 63)) * EE + (c >> 8) * 32 + (c & 3) * 8,
                           (char*)Bs + c * 16);
            }
        }

        // gelu (f32) -> bf16 (cvt_pk) -> wave-private swizzled G
        #pragma unroll
        for (int ni = 0; ni < 4; ++ni) {
            #pragma unroll
            for (int mi = 0; mi < 2; ++mi) {
                const int rloc = mi * 16 + lr;
                const float v0 = gelu_fast(acc[ni][mi][0]);
                const float v1 = gelu_fast(acc[ni][mi][1]);
                const float v2 = gelu_fast(acc[ni][mi][2]);
                const float v3 = gelu_fast(acc[ni][mi][3]);
                uint2 pk;
                pk.x = cvt_pk_bf16(v0, v1);
                pk.y = cvt_pk_bf16(v2, v3);
                const int byte = (rloc * 128 + (ni * 16 + g * 4) * 2) ^ ((rloc & 7) << 4);
                *(uint2*)(Gw + byte) = pk;
            }
        }

        // coalesced store: 4 passes x (8 rows x 128B); G is wave-private
        #pragma unroll
        for (int p = 0; p < 4; ++p) {
            const int rl = p * 8 + (l >> 3);
            const int hb = (l & 7) * 16;
            const uint4 v = *(const uint4*)(Gw + ((rl * 128 + hb) ^ ((rl & 7) << 4)));
            *(uint4*)((char*)(Wh + (size_t)(row0 + w * 32 + rl) * HH + col0 + ct * 64) + hb) = v;
        }
        __syncthreads();
    }
}

// ---------------------------------------------------------------------------
// Fused f-level kernel (r15/r16-validated 138 us), Wall written transposed.
// ---------------------------------------------------------------------------
__global__ __launch_bounds__(256, 3) void f_fused(
    const __hip_bfloat16* __restrict__ X,     // MM x EE (bf16)
    const __hip_bfloat16* __restrict__ W1t,   // NW x HH x EE (bf16)
    const float* __restrict__ b1,             // NW x HH
    const _Float16* __restrict__ W2t,         // NW x 16 x HH (f16)
    const float* __restrict__ b2,             // NW x NL
    float* __restrict__ Wall_t)               // [NW*16][MM]
{
    __shared__ __hip_bfloat16 Bs[8 * 64 * 32];        // 32 KB [kk][row][32]
    __shared__ __align__(16) char Gb[4][4096];        // per-wave G [32r][64h] f16
    __shared__ float biasS[HH];                       // 4 KB

    const int tid = threadIdx.x;
    const int w = tid >> 6, l = tid & 63;
    const int row0 = blockIdx.x * 128;
    const int m_lv = blockIdx.y;
    const int lr = l & 15;
    const int g  = l >> 4;
    const int lk = g * 8;

    const __hip_bfloat16* W1m = W1t + (size_t)m_lv * HH * EE;

    ((float4*)biasS)[tid] = ((const float4*)(b1 + (size_t)m_lv * HH))[tid];

    short8 xf[2][8];
    {
        const __hip_bfloat16* xp0 = X + (size_t)(row0 + w * 32 + lr) * EE + lk;
        #pragma unroll
        for (int kk = 0; kk < 8; ++kk) {
            xf[0][kk] = *(const short8*)(xp0 + kk * 32);
            xf[1][kk] = *(const short8*)(xp0 + 16 * EE + kk * 32);
        }
    }

    const _Float16* w2p = W2t + ((size_t)m_lv * 16 + lr) * HH + lk;
    char* Gw = Gb[w];

    f32x4 wacc0 = {}, wacc1 = {};

    #pragma unroll
    for (int rstep = 0; rstep < 8; ++rstep) {
        const int c = rstep * 256 + tid;
        load_lds16(W1m + (size_t)((c >> 2) & 63) * EE + (c >> 8) * 32 + (c & 3) * 8,
                   (char*)Bs + c * 16);
    }
    __syncthreads();

    #pragma unroll 1
    for (int ct = 0; ct < 16; ++ct) {
        // acc C-in = bias
        f32x4 acc[4][2];
        #pragma unroll
        for (int ni = 0; ni < 4; ++ni) {
            const float4 bv = *(const float4*)&biasS[ct * 64 + ni * 16 + g * 4];
            const f32x4 bi = {bv.x, bv.y, bv.z, bv.w};
            acc[ni][0] = bi;
            acc[ni][1] = bi;
        }
        __builtin_amdgcn_s_setprio(1);
        #pragma unroll
        for (int kk = 0; kk < 8; ++kk) {
            short8 a[4];
            #pragma unroll
            for (int ni = 0; ni < 4; ++ni)
                a[ni] = *(const short8*)((const char*)Bs +
                         (kk * 4096 + ni * 1024 + lr * 64 + g * 16));
            #pragma unroll
            for (int ni = 0; ni < 4; ++ni) {
                acc[ni][0] = __builtin_amdgcn_mfma_f32_16x16x32_bf16(a[ni], xf[0][kk], acc[ni][0], 0, 0, 0);
                acc[ni][1] = __builtin_amdgcn_mfma_f32_16x16x32_bf16(a[ni], xf[1][kk], acc[ni][1], 0, 0, 0);
            }
        }
        __builtin_amdgcn_s_setprio(0);
        __syncthreads();                       // all waves done reading Bs

        if (ct < 15) {
            const __hip_bfloat16* W1n = W1m + (size_t)(ct + 1) * 64 * EE;
            #pragma unroll
            for (int rstep = 0; rstep < 8; ++rstep) {
                const int c = rstep * 256 + tid;
                load_lds16(W1n + (size_t)((c >> 2) & 63) * EE + (c >> 8) * 32 + (c & 3) * 8,
                           (char*)Bs + c * 16);
            }
        }

        // gelu (packed f16) -> wave-private swizzled G (f16)
        #pragma unroll
        for (int ni = 0; ni < 4; ++ni) {
            #pragma unroll
            for (int mi = 0; mi < 2; ++mi) {
                const int rloc = mi * 16 + lr;
                uint2 pk;
                pk.x = gelu2_f16(acc[ni][mi][0], acc[ni][mi][1]);
                pk.y = gelu2_f16(acc[ni][mi][2], acc[ni][mi][3]);
                const int byte = (rloc * 128 + (ni * 16 + g * 4) * 2) ^ ((rloc & 7) << 4);
                *(uint2*)(Gw + byte) = pk;
            }
        }

        // mini-GEMM (f16): Wall-frag += W2t[ct k-range] x G
        #pragma unroll
        for (int ks2 = 0; ks2 < 2; ++ks2) {
            const half8 aw = *(const half8*)(w2p + ct * 64 + ks2 * 32);
            {
                const int byte = (lr * 128 + (ks2 * 32 + lk) * 2) ^ ((lr & 7) << 4);
                const half8 bg = *(const half8*)(Gw + byte);
                wacc0 = __builtin_amdgcn_mfma_f32_16x16x32_f16(aw, bg, wacc0, 0, 0, 0);
            }
            {
                const int rloc = 16 + lr;
                const int byte = (rloc * 128 + (ks2 * 32 + lk) * 2) ^ ((rloc & 7) << 4);
                const half8 bg = *(const half8*)(Gw + byte);
                wacc1 = __builtin_amdgcn_mfma_f32_16x16x32_f16(aw, bg, wacc1, 0, 0, 0);
            }
        }
        __syncthreads();                       // staging drained; Bs ready
    }

    // epilogue -> Wall_t[(m*16 + lval)*MM + r]
    const float* b2m = b2 + m_lv * NL;
    #pragma unroll
    for (int j = 0; j < 4; ++j) {
        const int lval = g * 4 + j;
        const float bv = (lval < NL) ? b2m[lval] : 0.f;
        float* wp = Wall_t + (size_t)(m_lv * 16 + lval) * MM;
        wp[row0 + w * 32 + lr]      = wacc0[j] + bv;
        wp[row0 + w * 32 + 16 + lr] = wacc1[j] + bv;
    }
}

// ---------------------------------------------------------------------------
// One prep kernel for ALL conversions/transposes.
// ---------------------------------------------------------------------------
struct bf4 { __hip_bfloat16 a, b, c, d; };

__device__ __forceinline__ void cvt_body(
    const float* __restrict__ in, __hip_bfloat16* __restrict__ out, int i)
{
    float4 v = ((const float4*)in)[i];
    bf4 o;
    o.a = __float2bfloat16(v.x); o.b = __float2bfloat16(v.y);
    o.c = __float2bfloat16(v.z); o.d = __float2bfloat16(v.w);
    ((bf4*)out)[i] = o;
}

__device__ __forceinline__ void transpose_body(
    const float* __restrict__ inB, __hip_bfloat16* __restrict__ outB,
    int K, int N, int bx, int by, float (*t)[33])
{
    const int n0 = bx * 32, k0 = by * 32;
    const int tx = threadIdx.x & 31, ty = threadIdx.x >> 5;  // 32 x 8
    #pragma unroll
    for (int i = 0; i < 32; i += 8)
        t[ty + i][tx] = inB[(size_t)(k0 + ty + i) * N + n0 + tx];
    __syncthreads();
    #pragma unroll
    for (int i = 0; i < 32; i += 8)
        outB[(size_t)(n0 + ty + i) * K + k0 + tx] = __float2bfloat16(t[tx][ty + i]);
}

__global__ __launch_bounds__(256) void prep_all(
    const float* __restrict__ V, const float* __restrict__ input,
    const float* __restrict__ g_W1, const float* __restrict__ g_W2,
    const float* __restrict__ f_W1, const float* __restrict__ f_W2,
    __hip_bfloat16* __restrict__ Vb, __hip_bfloat16* __restrict__ Xb,
    __hip_bfloat16* __restrict__ gW1t, __hip_bfloat16* __restrict__ gW2t,
    __hip_bfloat16* __restrict__ fW1t, _Float16* __restrict__ W2tA)
{
    __shared__ float t[32][33];
    const int bid = blockIdx.x;
    const int tid = threadIdx.x;

    if (bid < 4096) {
        cvt_body(V, Vb, bid * 256 + tid);
    } else if (bid < 8192) {
        cvt_body(input, Xb, (bid - 4096) * 256 + tid);
    } else if (bid < 8448) {
        const int b2 = bid - 8192;                   // g_W1: grid (32, 8)
        transpose_body(g_W1, gW1t, EE, HH, b2 & 31, b2 >> 5, t);
    } else if (bid < 8704) {
        const int b2 = bid - 8448;                   // g_W2: grid (8, 32)
        transpose_body(g_W2, gW2t, HH, EE, b2 & 7, b2 >> 3, t);
    } else if (bid < 11776) {
        const int b2 = bid - 8704;                   // f_W1: 12 x (32, 8)
        const int z = b2 >> 8, r = b2 & 255;
        transpose_body(f_W1 + (size_t)z * EE * HH, fW1t + (size_t)z * HH * EE,
                       EE, HH, r & 31, r >> 5, t);
    } else {
        const int idx = (bid - 11776) * 256 + tid;   // w2t: NW*16*HH elems, f16
        const int m = idx >> 14;
        const int n = (idx >> 10) & 15;
        const int h = idx & 1023;
        const float v = (n < NL) ? f_W2[((size_t)m * HH + h) * NL + n] : 0.f;
        W2tA[idx] = (_Float16)v;
    }
}

// ---------------------------------------------------------------------------
// ALL 12 chord steps in ONE kernel, state resident in LDS (r19-validated).
// r19 ran 512 thr (8 waves/CU, 25% occ) -- latency not hidden. Now 1024 thr,
// 4 rows/thread: 16 waves/CU at identical work, layout and LDS (64 KB).
// ---------------------------------------------------------------------------
__global__ __launch_bounds__(1024, 1) void chord_lds(
    const uint2* __restrict__ Vg,     // MM x 64 (4 bf16 per slot) initial state
    const float* __restrict__ Wall_t, // [NW*16][MM]
    float4* __restrict__ outF)        // MM x 64 (f32 x4) final output
{
    __shared__ unsigned L[2][2][NN];   // [buf][ch-pair][row]  64 KB

    const int tid = threadIdx.x;       // 0..1023
    const int bid = blockIdx.x;        // 0..255
    const int batch = bid >> 6;
    const int slice = bid & 63;        // 4-channel slice
    const int gbase = batch * NN;

    // init: load own 4 rows from global (bf16 x4 per row)
    #pragma unroll
    for (int i = 0; i < 4; ++i) {
        const int n = tid + i * 1024;
        const uint2 u = Vg[(size_t)(gbase + n) * 64 + slice];
        L[0][0][n] = u.x;
        L[0][1][n] = u.y;
    }
    __syncthreads();

    int cur = 0;
    #pragma unroll 1
    for (int m = 0; m < NW; ++m) {
        const float* wbase = Wall_t + (size_t)m * 16 * MM + gbase;
        const int nxt = cur ^ 1;
        #pragma unroll 1
        for (int i = 0; i < 4; ++i) {
            const int n = tid + i * 1024;
            float a0, a1, a2, a3;
            unpack2(L[cur][0][n], a0, a1);
            unpack2(L[cur][1][n], a2, a3);
            #pragma unroll
            for (int l = 0; l < NL; ++l) {
                const int off = (l == 0) ? 0 : (1 << (l - 1));
                const int cn = (n + off) & (NN - 1);
                const float wv = wbase[(size_t)l * MM + n];
                float x0, x1, x2, x3;
                unpack2(L[cur][0][cn], x0, x1);
                unpack2(L[cur][1][cn], x2, x3);
                a0 = __builtin_fmaf(wv, x0, a0);
                a1 = __builtin_fmaf(wv, x1, a1);
                a2 = __builtin_fmaf(wv, x2, a2);
                a3 = __builtin_fmaf(wv, x3, a3);
            }
            if (m == NW - 1) {
                float4 o = {a0, a1, a2, a3};
                outF[(size_t)(gbase + n) * 64 + slice] = o;
            } else {
                L[nxt][0][n] = pack_bf16_rh(a0, a1);
                L[nxt][1][n] = pack_bf16_rh(a2, a3);
            }
        }
        __syncthreads();
        cur ^= 1;
    }
}

// ---------------------------------------------------------------------------
extern "C" void kernel_launch(void* const* d_in, const int* in_sizes, int n_in,
                              void* d_out, int out_size, void* d_ws, size_t ws_size,
                              hipStream_t stream)
{
    const float* V      = (const float*)d_in[0];
    const float* input  = (const float*)d_in[1];
    const float* g_W1   = (const float*)d_in[2];
    const float* g_b1   = (const float*)d_in[3];
    const float* g_W2   = (const float*)d_in[4];
    const float* g_b2   = (const float*)d_in[5];
    const float* f_W1   = (const float*)d_in[6];
    const float* f_b1   = (const float*)d_in[7];
    const float* f_W2   = (const float*)d_in[8];
    const float* f_b2   = (const float*)d_in[9];
    float* out = (float*)d_out;

    char* ws = (char*)d_ws;
    size_t o = 0;
    __hip_bfloat16* Vb     = (__hip_bfloat16*)(ws + o); o += (size_t)MM * EE * 2;        // 8 MB
    __hip_bfloat16* Xb     = (__hip_bfloat16*)(ws + o); o += (size_t)MM * EE * 2;        // 8 MB
    __hip_bfloat16* gW1t   = (__hip_bfloat16*)(ws + o); o += (size_t)HH * EE * 2;        // 512 KB
    __hip_bfloat16* gW2t   = (__hip_bfloat16*)(ws + o); o += (size_t)EE * HH * 2;        // 512 KB
    __hip_bfloat16* fW1t   = (__hip_bfloat16*)(ws + o); o += (size_t)NW * HH * EE * 2;   // 6 MB
    _Float16*       W2tA   = (_Float16*)(ws + o);       o += (size_t)NW * 16 * HH * 2;   // 384 KB
    __hip_bfloat16* Whb    = (__hip_bfloat16*)(ws + o); o += (size_t)MM * HH * 2;        // 32 MB (gate only)
    float*          Wall   = (float*)(ws + o);          o += (size_t)NW * 16 * MM * 4;   // 12 MB (transposed)
    __hip_bfloat16* Vg0    = (__hip_bfloat16*)(ws + o); o += (size_t)MM * EE * 2;        // 8 MB

    dim3 blk(256);

    // 0. ALL dtype conversion / weight transposes in one launch
    prep_all<<<12544, blk, 0, stream>>>(V, input, g_W1, g_W2, f_W1, f_W2,
                                        Vb, Xb, gW1t, gW2t, fW1t, W2tA);

    // 1. Gate gemm1: A-in-registers, bf16 output (r14/r16-validated)
    gemm1_areg<<<dim3(MM / 128, HH / 128), blk, 0, stream>>>(Vb, gW1t, g_b1, Whb);
    // 2. Gate gemm2 (K=1024), bf16 MFMA, bf16 out -> Vg0
    gemm_bf16<__hip_bfloat16, false><<<dim3(EE / 128, MM / 128), blk, 0, stream>>>(
        Whb, gW2t, g_b2, Vg0, MM, EE, HH);

    // 3. All 12 levels' link weights in ONE fused launch (Wall transposed)
    f_fused<<<dim3(MM / 128, NW), blk, 0, stream>>>(Xb, fW1t, f_b1, W2tA, f_b2, Wall);

    // 4. ALL 12 chord steps in ONE launch, LDS-resident state (1024 thr)
    chord_lds<<<256, dim3(1024), 0, stream>>>((const uint2*)Vg0, Wall, (float4*)out);
}

// Round 21
// 257.724 us; speedup vs baseline: 1.2784x; 1.0248x over previous
//
#include <hip/hip_runtime.h>
#include <hip/hip_bf16.h>
#include <hip/hip_fp16.h>
#include <math.h>

// Problem constants
#define BB 4
#define NN 4096
#define EE 256
#define HH 1024
#define NW 12
#define NL 13
#define MM (BB * NN)   // 16384 rows

typedef __attribute__((ext_vector_type(8))) short short8;   // 8x16b (4 VGPRs)
typedef __attribute__((ext_vector_type(4))) float f32x4;
typedef __attribute__((ext_vector_type(2))) _Float16 h2;    // packed f16 pair
typedef __attribute__((ext_vector_type(8))) _Float16 half8; // f16 MFMA frag

// Fast gelu, f32 scalar: x*sigmoid(1.5957691(x+0.044715x^3)), exp2 form.
__device__ __forceinline__ float gelu_fast(float x) {
    float t = __builtin_fmaf(0.044715f, x * x, 1.0f);
    float e = __builtin_amdgcn_exp2f(-2.3021193f * (x * t));
    return x * __builtin_amdgcn_rcpf(1.0f + e);
}

// Packed-f16 gelu on a pair of f32 inputs -> packed f16 pair bits (r15: -7us).
__device__ __forceinline__ unsigned gelu2_f16(float a, float b) {
    const h2 C1 = {(_Float16)-2.3021193f, (_Float16)-2.3021193f};
    const h2 C2 = {(_Float16)0.044715f, (_Float16)0.044715f};
    const h2 ONE = {(_Float16)1.0f, (_Float16)1.0f};
    h2 x;
    asm("v_cvt_pkrtz_f16_f32 %0, %1, %2" : "=v"(x) : "v"(a), "v"(b));
    h2 x2 = x * x;
    h2 t  = C2 * x2 + ONE;          // v_pk_fma_f16
    h2 z  = (C1 * x) * t;
    __half2 es = h2exp2(__builtin_bit_cast(__half2, z));
    h2 d = ONE + __builtin_bit_cast(h2, es);
    __half2 rs = h2rcp(__builtin_bit_cast(__half2, d));
    h2 y = x * __builtin_bit_cast(h2, rs);
    return __builtin_bit_cast(unsigned, y);
}

// HW packed f32->2xf16 (RTZ), 1 VALU op.
__device__ __forceinline__ h2 cvt_pk_f16(float a, float b) {
    h2 r;
    asm("v_cvt_pkrtz_f16_f32 %0, %1, %2" : "=v"(r) : "v"(a), "v"(b));
    return r;
}

// HW packed f32->2xbf16 (RNE), 1 VALU op.
__device__ __forceinline__ unsigned cvt_pk_bf16(float a, float b) {
    unsigned r;
    asm("v_cvt_pk_bf16_f32 %0, %1, %2" : "=v"(r) : "v"(a), "v"(b));
    return r;
}

__device__ __forceinline__ void load_lds16(const void* g, void* l) {
    __builtin_amdgcn_global_load_lds(
        (const __attribute__((address_space(1))) void*)g,
        (__attribute__((address_space(3))) void*)l, 16, 0, 0);
}

// ---------------------------------------------------------------------------
// MFMA GEMM (m97 structure). OutT selects store conversion:
// float -> f32, _Float16 -> f16, else bf16. Used for gate gemm2 (K=1024).
// ---------------------------------------------------------------------------
template<typename OutT, bool GELU>
__global__ __launch_bounds__(256) void gemm_bf16(
    const __hip_bfloat16* __restrict__ A,   // M x K  row-major
    const __hip_bfloat16* __restrict__ Bt,  // N x K  row-major (pre-transposed)
    const float* __restrict__ bias,         // N
    OutT* __restrict__ C,                   // M x N
    int M, int N, int K)
{
    __shared__ __hip_bfloat16 As[128 * 32];
    __shared__ __hip_bfloat16 Bs[128 * 32];

    const int tid = threadIdx.x;
    const int w = tid >> 6, l = tid & 63;
    const int wr = w >> 1, wc = w & 1;       // 2x2 wave grid, each 64x64
    const int row0 = blockIdx.y * 128;
    const int col0 = blockIdx.x * 128;

    const int c0 = w * 64 + l;
    const int c1 = c0 + 256;
    const __hip_bfloat16* gA0 = A  + (size_t)(row0 + (c0 >> 2)) * K + (c0 & 3) * 8;
    const __hip_bfloat16* gA1 = A  + (size_t)(row0 + (c1 >> 2)) * K + (c1 & 3) * 8;
    const __hip_bfloat16* gB0 = Bt + (size_t)(col0 + (c0 >> 2)) * K + (c0 & 3) * 8;
    const __hip_bfloat16* gB1 = Bt + (size_t)(col0 + (c1 >> 2)) * K + (c1 & 3) * 8;
    char* dA0 = (char*)As + w * 1024;
    char* dA1 = (char*)As + w * 1024 + 4096;
    char* dB0 = (char*)Bs + w * 1024;
    char* dB1 = (char*)Bs + w * 1024 + 4096;

    const int lr = l & 15;
    const int lk = (l >> 4) * 8;

    f32x4 acc[4][4] = {};

    for (int k0 = 0; k0 < K; k0 += 32) {
        load_lds16(gA0 + k0, dA0);
        load_lds16(gA1 + k0, dA1);
        load_lds16(gB0 + k0, dB0);
        load_lds16(gB1 + k0, dB1);
        __syncthreads();

        short8 a[4], b[4];
        #pragma unroll
        for (int m = 0; m < 4; ++m)
            a[m] = *(const short8*)&As[(wr * 64 + m * 16 + lr) * 32 + lk];
        #pragma unroll
        for (int n = 0; n < 4; ++n)
            b[n] = *(const short8*)&Bs[(wc * 64 + n * 16 + lr) * 32 + lk];
        #pragma unroll
        for (int m = 0; m < 4; ++m)
            #pragma unroll
            for (int n = 0; n < 4; ++n)
                acc[m][n] = __builtin_amdgcn_mfma_f32_16x16x32_bf16(a[m], b[n], acc[m][n], 0, 0, 0);
        __syncthreads();
    }

    #pragma unroll
    for (int m = 0; m < 4; ++m) {
        #pragma unroll
        for (int n = 0; n < 4; ++n) {
            const int col = col0 + wc * 64 + n * 16 + lr;
            const float bv = bias[col];
            #pragma unroll
            for (int j = 0; j < 4; ++j) {
                const int row = row0 + wr * 64 + m * 16 + (l >> 4) * 4 + j;
                float v = acc[m][n][j] + bv;
                if (GELU) v = gelu_fast(v);
                if constexpr (__is_same(OutT, float))
                    C[(size_t)row * N + col] = v;
                else if constexpr (__is_same(OutT, _Float16))
                    C[(size_t)row * N + col] = (_Float16)v;
                else
                    C[(size_t)row * N + col] = __float2bfloat16(v);
            }
        }
    }
}

// ---------------------------------------------------------------------------
// Gate gemm1, A-in-registers (r14/r16-validated): Wh(bf16) = gelu(Vb@W1+b1).
// ---------------------------------------------------------------------------
__global__ __launch_bounds__(256, 3) void gemm1_areg(
    const __hip_bfloat16* __restrict__ A,     // MM x EE (Vb)
    const __hip_bfloat16* __restrict__ W1t,   // HH x EE
    const float* __restrict__ b1,             // HH
    __hip_bfloat16* __restrict__ Wh)          // MM x HH
{
    __shared__ __hip_bfloat16 Bs[8 * 64 * 32];   // 32 KB [kk][row][32]
    __shared__ __align__(16) char Gb[4][4096];   // per-wave G [32r][64h]

    const int tid = threadIdx.x;
    const int w = tid >> 6, l = tid & 63;
    const int row0 = blockIdx.x * 128;
    const int col0 = blockIdx.y * 128;
    const int lr = l & 15, g = l >> 4, lk = g * 8;

    short8 xf[2][8];
    {
        const __hip_bfloat16* xp0 = A + (size_t)(row0 + w * 32 + lr) * EE + lk;
        #pragma unroll
        for (int kk = 0; kk < 8; ++kk) {
            xf[0][kk] = *(const short8*)(xp0 + kk * 32);
            xf[1][kk] = *(const short8*)(xp0 + 16 * EE + kk * 32);
        }
    }
    char* Gw = Gb[w];

    #pragma unroll
    for (int rstep = 0; rstep < 8; ++rstep) {
        const int c = rstep * 256 + tid;
        load_lds16(W1t + (size_t)(col0 + ((c >> 2) & 63)) * EE + (c >> 8) * 32 + (c & 3) * 8,
                   (char*)Bs + c * 16);
    }
    __syncthreads();

    #pragma unroll 1
    for (int ct = 0; ct < 2; ++ct) {
        f32x4 acc[4][2];
        #pragma unroll
        for (int ni = 0; ni < 4; ++ni) {
            const float4 bv = *(const float4*)&b1[col0 + ct * 64 + ni * 16 + g * 4];
            const f32x4 bi = {bv.x, bv.y, bv.z, bv.w};
            acc[ni][0] = bi;
            acc[ni][1] = bi;
        }
        __builtin_amdgcn_s_setprio(1);
        #pragma unroll
        for (int kk = 0; kk < 8; ++kk) {
            short8 a[4];
            #pragma unroll
            for (int ni = 0; ni < 4; ++ni)
                a[ni] = *(const short8*)((const char*)Bs +
                         (kk * 4096 + ni * 1024 + lr * 64 + g * 16));
            #pragma unroll
            for (int ni = 0; ni < 4; ++ni) {
                acc[ni][0] = __builtin_amdgcn_mfma_f32_16x16x32_bf16(a[ni], xf[0][kk], acc[ni][0], 0, 0, 0);
                acc[ni][1] = __builtin_amdgcn_mfma_f32_16x16x32_bf16(a[ni], xf[1][kk], acc[ni][1], 0, 0, 0);
            }
        }
        __builtin_amdgcn_s_setprio(0);
        __syncthreads();

        if (ct == 0) {
            #pragma unroll
            for (int rstep = 0; rstep < 8; ++rstep) {
                const int c = rstep * 256 + tid;
                load_lds16(W1t + (size_t)(col0 + 64 + ((c >> 2) & 63)) * EE + (c >> 8) * 32 + (c & 3) * 8,
                           (char*)Bs + c * 16);
            }
        }

        // gelu (f32) -> bf16 (cvt_pk) -> wave-private swizzled G
        #pragma unroll
        for (int ni = 0; ni < 4; ++ni) {
            #pragma unroll
            for (int mi = 0; mi < 2; ++mi) {
                const int rloc = mi * 16 + lr;
                const float v0 = gelu_fast(acc[ni][mi][0]);
                const float v1 = gelu_fast(acc[ni][mi][1]);
                const float v2 = gelu_fast(acc[ni][mi][2]);
                const float v3 = gelu_fast(acc[ni][mi][3]);
                uint2 pk;
                pk.x = cvt_pk_bf16(v0, v1);
                pk.y = cvt_pk_bf16(v2, v3);
                const int byte = (rloc * 128 + (ni * 16 + g * 4) * 2) ^ ((rloc & 7) << 4);
                *(uint2*)(Gw + byte) = pk;
            }
        }

        // coalesced store: 4 passes x (8 rows x 128B); G is wave-private
        #pragma unroll
        for (int p = 0; p < 4; ++p) {
            const int rl = p * 8 + (l >> 3);
            const int hb = (l & 7) * 16;
            const uint4 v = *(const uint4*)(Gw + ((rl * 128 + hb) ^ ((rl & 7) << 4)));
            *(uint4*)((char*)(Wh + (size_t)(row0 + w * 32 + rl) * HH + col0 + ct * 64) + hb) = v;
        }
        __syncthreads();
    }
}

// ---------------------------------------------------------------------------
// Fused f-level kernel (r15/r16-validated 138 us), Wall written transposed.
// ---------------------------------------------------------------------------
__global__ __launch_bounds__(256, 3) void f_fused(
    const __hip_bfloat16* __restrict__ X,     // MM x EE (bf16)
    const __hip_bfloat16* __restrict__ W1t,   // NW x HH x EE (bf16)
    const float* __restrict__ b1,             // NW x HH
    const _Float16* __restrict__ W2t,         // NW x 16 x HH (f16)
    const float* __restrict__ b2,             // NW x NL
    float* __restrict__ Wall_t)               // [NW*16][MM]
{
    __shared__ __hip_bfloat16 Bs[8 * 64 * 32];        // 32 KB [kk][row][32]
    __shared__ __align__(16) char Gb[4][4096];        // per-wave G [32r][64h] f16
    __shared__ float biasS[HH];                       // 4 KB

    const int tid = threadIdx.x;
    const int w = tid >> 6, l = tid & 63;
    const int row0 = blockIdx.x * 128;
    const int m_lv = blockIdx.y;
    const int lr = l & 15;
    const int g  = l >> 4;
    const int lk = g * 8;

    const __hip_bfloat16* W1m = W1t + (size_t)m_lv * HH * EE;

    ((float4*)biasS)[tid] = ((const float4*)(b1 + (size_t)m_lv * HH))[tid];

    short8 xf[2][8];
    {
        const __hip_bfloat16* xp0 = X + (size_t)(row0 + w * 32 + lr) * EE + lk;
        #pragma unroll
        for (int kk = 0; kk < 8; ++kk) {
            xf[0][kk] = *(const short8*)(xp0 + kk * 32);
            xf[1][kk] = *(const short8*)(xp0 + 16 * EE + kk * 32);
        }
    }

    const _Float16* w2p = W2t + ((size_t)m_lv * 16 + lr) * HH + lk;
    char* Gw = Gb[w];

    f32x4 wacc0 = {}, wacc1 = {};

    #pragma unroll
    for (int rstep = 0; rstep < 8; ++rstep) {
        const int c = rstep * 256 + tid;
        load_lds16(W1m + (size_t)((c >> 2) & 63) * EE + (c >> 8) * 32 + (c & 3) * 8,
                   (char*)Bs + c * 16);
    }
    __syncthreads();

    #pragma unroll 1
    for (int ct = 0; ct < 16; ++ct) {
        // acc C-in = bias
        f32x4 acc[4][2];
        #pragma unroll
        for (int ni = 0; ni < 4; ++ni) {
            const float4 bv = *(const float4*)&biasS[ct * 64 + ni * 16 + g * 4];
            const f32x4 bi = {bv.x, bv.y, bv.z, bv.w};
            acc[ni][0] = bi;
            acc[ni][1] = bi;
        }
        __builtin_amdgcn_s_setprio(1);
        #pragma unroll
        for (int kk = 0; kk < 8; ++kk) {
            short8 a[4];
            #pragma unroll
            for (int ni = 0; ni < 4; ++ni)
                a[ni] = *(const short8*)((const char*)Bs +
                         (kk * 4096 + ni * 1024 + lr * 64 + g * 16));
            #pragma unroll
            for (int ni = 0; ni < 4; ++ni) {
                acc[ni][0] = __builtin_amdgcn_mfma_f32_16x16x32_bf16(a[ni], xf[0][kk], acc[ni][0], 0, 0, 0);
                acc[ni][1] = __builtin_amdgcn_mfma_f32_16x16x32_bf16(a[ni], xf[1][kk], acc[ni][1], 0, 0, 0);
            }
        }
        __builtin_amdgcn_s_setprio(0);
        __syncthreads();                       // all waves done reading Bs

        if (ct < 15) {
            const __hip_bfloat16* W1n = W1m + (size_t)(ct + 1) * 64 * EE;
            #pragma unroll
            for (int rstep = 0; rstep < 8; ++rstep) {
                const int c = rstep * 256 + tid;
                load_lds16(W1n + (size_t)((c >> 2) & 63) * EE + (c >> 8) * 32 + (c & 3) * 8,
                           (char*)Bs + c * 16);
            }
        }

        // gelu (packed f16) -> wave-private swizzled G (f16)
        #pragma unroll
        for (int ni = 0; ni < 4; ++ni) {
            #pragma unroll
            for (int mi = 0; mi < 2; ++mi) {
                const int rloc = mi * 16 + lr;
                uint2 pk;
                pk.x = gelu2_f16(acc[ni][mi][0], acc[ni][mi][1]);
                pk.y = gelu2_f16(acc[ni][mi][2], acc[ni][mi][3]);
                const int byte = (rloc * 128 + (ni * 16 + g * 4) * 2) ^ ((rloc & 7) << 4);
                *(uint2*)(Gw + byte) = pk;
            }
        }

        // mini-GEMM (f16): Wall-frag += W2t[ct k-range] x G
        #pragma unroll
        for (int ks2 = 0; ks2 < 2; ++ks2) {
            const half8 aw = *(const half8*)(w2p + ct * 64 + ks2 * 32);
            {
                const int byte = (lr * 128 + (ks2 * 32 + lk) * 2) ^ ((lr & 7) << 4);
                const half8 bg = *(const half8*)(Gw + byte);
                wacc0 = __builtin_amdgcn_mfma_f32_16x16x32_f16(aw, bg, wacc0, 0, 0, 0);
            }
            {
                const int rloc = 16 + lr;
                const int byte = (rloc * 128 + (ks2 * 32 + lk) * 2) ^ ((rloc & 7) << 4);
                const half8 bg = *(const half8*)(Gw + byte);
                wacc1 = __builtin_amdgcn_mfma_f32_16x16x32_f16(aw, bg, wacc1, 0, 0, 0);
            }
        }
        __syncthreads();                       // staging drained; Bs ready
    }

    // epilogue -> Wall_t[(m*16 + lval)*MM + r]
    const float* b2m = b2 + m_lv * NL;
    #pragma unroll
    for (int j = 0; j < 4; ++j) {
        const int lval = g * 4 + j;
        const float bv = (lval < NL) ? b2m[lval] : 0.f;
        float* wp = Wall_t + (size_t)(m_lv * 16 + lval) * MM;
        wp[row0 + w * 32 + lr]      = wacc0[j] + bv;
        wp[row0 + w * 32 + 16 + lr] = wacc1[j] + bv;
    }
}

// ---------------------------------------------------------------------------
// One prep kernel for ALL conversions/transposes.
// ---------------------------------------------------------------------------
struct bf4 { __hip_bfloat16 a, b, c, d; };

__device__ __forceinline__ void cvt_body(
    const float* __restrict__ in, __hip_bfloat16* __restrict__ out, int i)
{
    float4 v = ((const float4*)in)[i];
    bf4 o;
    o.a = __float2bfloat16(v.x); o.b = __float2bfloat16(v.y);
    o.c = __float2bfloat16(v.z); o.d = __float2bfloat16(v.w);
    ((bf4*)out)[i] = o;
}

__device__ __forceinline__ void transpose_body(
    const float* __restrict__ inB, __hip_bfloat16* __restrict__ outB,
    int K, int N, int bx, int by, float (*t)[33])
{
    const int n0 = bx * 32, k0 = by * 32;
    const int tx = threadIdx.x & 31, ty = threadIdx.x >> 5;  // 32 x 8
    #pragma unroll
    for (int i = 0; i < 32; i += 8)
        t[ty + i][tx] = inB[(size_t)(k0 + ty + i) * N + n0 + tx];
    __syncthreads();
    #pragma unroll
    for (int i = 0; i < 32; i += 8)
        outB[(size_t)(n0 + ty + i) * K + k0 + tx] = __float2bfloat16(t[tx][ty + i]);
}

__global__ __launch_bounds__(256) void prep_all(
    const float* __restrict__ V, const float* __restrict__ input,
    const float* __restrict__ g_W1, const float* __restrict__ g_W2,
    const float* __restrict__ f_W1, const float* __restrict__ f_W2,
    __hip_bfloat16* __restrict__ Vb, __hip_bfloat16* __restrict__ Xb,
    __hip_bfloat16* __restrict__ gW1t, __hip_bfloat16* __restrict__ gW2t,
    __hip_bfloat16* __restrict__ fW1t, _Float16* __restrict__ W2tA)
{
    __shared__ float t[32][33];
    const int bid = blockIdx.x;
    const int tid = threadIdx.x;

    if (bid < 4096) {
        cvt_body(V, Vb, bid * 256 + tid);
    } else if (bid < 8192) {
        cvt_body(input, Xb, (bid - 4096) * 256 + tid);
    } else if (bid < 8448) {
        const int b2 = bid - 8192;                   // g_W1: grid (32, 8)
        transpose_body(g_W1, gW1t, EE, HH, b2 & 31, b2 >> 5, t);
    } else if (bid < 8704) {
        const int b2 = bid - 8448;                   // g_W2: grid (8, 32)
        transpose_body(g_W2, gW2t, HH, EE, b2 & 7, b2 >> 3, t);
    } else if (bid < 11776) {
        const int b2 = bid - 8704;                   // f_W1: 12 x (32, 8)
        const int z = b2 >> 8, r = b2 & 255;
        transpose_body(f_W1 + (size_t)z * EE * HH, fW1t + (size_t)z * HH * EE,
                       EE, HH, r & 31, r >> 5, t);
    } else {
        const int idx = (bid - 11776) * 256 + tid;   // w2t: NW*16*HH elems, f16
        const int m = idx >> 14;
        const int n = (idx >> 10) & 15;
        const int h = idx & 1023;
        const float v = (n < NL) ? f_W2[((size_t)m * HH + h) * NL + n] : 0.f;
        W2tA[idx] = (_Float16)v;
    }
}

// ---------------------------------------------------------------------------
// ALL 12 chord steps in ONE kernel, PACKED-F16 state resident in LDS.
// v_pk_fma_f16: per gather 1 cvt_pkrtz (weight splat) + 2 pk-FMA for 4
// channels (was 8 unpack + 4 f32 FMA). f16 state (10-bit mantissa) is
// strictly more precise than the previous bf16 state for |V| < 65504.
// 256 blocks x 1024 threads (16 waves/CU), 4 rows/thread, 64 KB LDS dbuf.
// ---------------------------------------------------------------------------
__global__ __launch_bounds__(1024, 1) void chord_lds(
    const uint2* __restrict__ Vg,     // MM x 64 (2x packed-f16 per slot)
    const float* __restrict__ Wall_t, // [NW*16][MM]
    float4* __restrict__ outF)        // MM x 64 (f32 x4) final output
{
    __shared__ unsigned L[2][2][NN];   // [buf][ch-pair][row]  64 KB

    const int tid = threadIdx.x;       // 0..1023
    const int bid = blockIdx.x;        // 0..255
    const int batch = bid >> 6;
    const int slice = bid & 63;        // 4-channel slice
    const int gbase = batch * NN;

    // init: load own 4 rows from global (f16 x4 per row, already packed)
    #pragma unroll
    for (int i = 0; i < 4; ++i) {
        const int n = tid + i * 1024;
        const uint2 u = Vg[(size_t)(gbase + n) * 64 + slice];
        L[0][0][n] = u.x;
        L[0][1][n] = u.y;
    }
    __syncthreads();

    int cur = 0;
    #pragma unroll 1
    for (int m = 0; m < NW; ++m) {
        const float* wbase = Wall_t + (size_t)m * 16 * MM + gbase;
        const int nxt = cur ^ 1;
        #pragma unroll 1
        for (int i = 0; i < 4; ++i) {
            const int n = tid + i * 1024;
            h2 a01 = __builtin_bit_cast(h2, L[cur][0][n]);
            h2 a23 = __builtin_bit_cast(h2, L[cur][1][n]);
            #pragma unroll
            for (int l = 0; l < NL; ++l) {
                const int off = (l == 0) ? 0 : (1 << (l - 1));
                const int cn = (n + off) & (NN - 1);
                const float wv = wbase[(size_t)l * MM + n];
                const h2 w2 = cvt_pk_f16(wv, wv);
                const h2 x01 = __builtin_bit_cast(h2, L[cur][0][cn]);
                const h2 x23 = __builtin_bit_cast(h2, L[cur][1][cn]);
                a01 = w2 * x01 + a01;          // v_pk_fma_f16
                a23 = w2 * x23 + a23;
            }
            if (m == NW - 1) {
                float4 o = {(float)a01[0], (float)a01[1],
                            (float)a23[0], (float)a23[1]};
                outF[(size_t)(gbase + n) * 64 + slice] = o;
            } else {
                L[nxt][0][n] = __builtin_bit_cast(unsigned, a01);
                L[nxt][1][n] = __builtin_bit_cast(unsigned, a23);
            }
        }
        __syncthreads();
        cur ^= 1;
    }
}

// ---------------------------------------------------------------------------
extern "C" void kernel_launch(void* const* d_in, const int* in_sizes, int n_in,
                              void* d_out, int out_size, void* d_ws, size_t ws_size,
                              hipStream_t stream)
{
    const float* V      = (const float*)d_in[0];
    const float* input  = (const float*)d_in[1];
    const float* g_W1   = (const float*)d_in[2];
    const float* g_b1   = (const float*)d_in[3];
    const float* g_W2   = (const float*)d_in[4];
    const float* g_b2   = (const float*)d_in[5];
    const float* f_W1   = (const float*)d_in[6];
    const float* f_b1   = (const float*)d_in[7];
    const float* f_W2   = (const float*)d_in[8];
    const float* f_b2   = (const float*)d_in[9];
    float* out = (float*)d_out;

    char* ws = (char*)d_ws;
    size_t o = 0;
    __hip_bfloat16* Vb     = (__hip_bfloat16*)(ws + o); o += (size_t)MM * EE * 2;        // 8 MB
    __hip_bfloat16* Xb     = (__hip_bfloat16*)(ws + o); o += (size_t)MM * EE * 2;        // 8 MB
    __hip_bfloat16* gW1t   = (__hip_bfloat16*)(ws + o); o += (size_t)HH * EE * 2;        // 512 KB
    __hip_bfloat16* gW2t   = (__hip_bfloat16*)(ws + o); o += (size_t)EE * HH * 2;        // 512 KB
    __hip_bfloat16* fW1t   = (__hip_bfloat16*)(ws + o); o += (size_t)NW * HH * EE * 2;   // 6 MB
    _Float16*       W2tA   = (_Float16*)(ws + o);       o += (size_t)NW * 16 * HH * 2;   // 384 KB
    __hip_bfloat16* Whb    = (__hip_bfloat16*)(ws + o); o += (size_t)MM * HH * 2;        // 32 MB (gate only)
    float*          Wall   = (float*)(ws + o);          o += (size_t)NW * 16 * MM * 4;   // 12 MB (transposed)
    _Float16*       Vg0    = (_Float16*)(ws + o);       o += (size_t)MM * EE * 2;        // 8 MB (f16 state)

    dim3 blk(256);

    // 0. ALL dtype conversion / weight transposes in one launch
    prep_all<<<12544, blk, 0, stream>>>(V, input, g_W1, g_W2, f_W1, f_W2,
                                        Vb, Xb, gW1t, gW2t, fW1t, W2tA);

    // 1. Gate gemm1: A-in-registers, bf16 output (r14/r16-validated)
    gemm1_areg<<<dim3(MM / 128, HH / 128), blk, 0, stream>>>(Vb, gW1t, g_b1, Whb);
    // 2. Gate gemm2 (K=1024), bf16 MFMA, F16 state out -> Vg0
    gemm_bf16<_Float16, false><<<dim3(EE / 128, MM / 128), blk, 0, stream>>>(
        Whb, gW2t, g_b2, Vg0, MM, EE, HH);

    // 3. All 12 levels' link weights in ONE fused launch (Wall transposed)
    f_fused<<<dim3(MM / 128, NW), blk, 0, stream>>>(Xb, fW1t, f_b1, W2tA, f_b2, Wall);

    // 4. ALL 12 chord steps in ONE launch, packed-f16 LDS-resident state
    chord_lds<<<256, dim3(1024), 0, stream>>>((const uint2*)Vg0, Wall, (float4*)out);
}

// Round 22
// 250.668 us; speedup vs baseline: 1.3144x; 1.0282x over previous
//
#include <hip/hip_runtime.h>
#include <hip/hip_bf16.h>
#include <hip/hip_fp16.h>
#include <math.h>

// Problem constants
#define BB 4
#define NN 4096
#define EE 256
#define HH 1024
#define NW 12
#define NL 13
#define MM (BB * NN)   // 16384 rows

typedef __attribute__((ext_vector_type(8))) short short8;   // 8x16b (4 VGPRs)
typedef __attribute__((ext_vector_type(4))) float f32x4;
typedef __attribute__((ext_vector_type(2))) _Float16 h2;    // packed f16 pair
typedef __attribute__((ext_vector_type(8))) _Float16 half8; // f16 MFMA frag

// Fast gelu, f32 scalar: x*sigmoid(1.5957691(x+0.044715x^3)), exp2 form.
__device__ __forceinline__ float gelu_fast(float x) {
    float t = __builtin_fmaf(0.044715f, x * x, 1.0f);
    float e = __builtin_amdgcn_exp2f(-2.3021193f * (x * t));
    return x * __builtin_amdgcn_rcpf(1.0f + e);
}

// Packed-f16 gelu on a pair of f32 inputs -> packed f16 pair bits (r15: -7us).
__device__ __forceinline__ unsigned gelu2_f16(float a, float b) {
    const h2 C1 = {(_Float16)-2.3021193f, (_Float16)-2.3021193f};
    const h2 C2 = {(_Float16)0.044715f, (_Float16)0.044715f};
    const h2 ONE = {(_Float16)1.0f, (_Float16)1.0f};
    h2 x;
    asm("v_cvt_pkrtz_f16_f32 %0, %1, %2" : "=v"(x) : "v"(a), "v"(b));
    h2 x2 = x * x;
    h2 t  = C2 * x2 + ONE;          // v_pk_fma_f16
    h2 z  = (C1 * x) * t;
    __half2 es = h2exp2(__builtin_bit_cast(__half2, z));
    h2 d = ONE + __builtin_bit_cast(h2, es);
    __half2 rs = h2rcp(__builtin_bit_cast(__half2, d));
    h2 y = x * __builtin_bit_cast(h2, rs);
    return __builtin_bit_cast(unsigned, y);
}

// HW packed f32->2xf16 (RTZ), 1 VALU op.
__device__ __forceinline__ h2 cvt_pk_f16(float a, float b) {
    h2 r;
    asm("v_cvt_pkrtz_f16_f32 %0, %1, %2" : "=v"(r) : "v"(a), "v"(b));
    return r;
}

// HW packed f32->2xbf16 (RNE), 1 VALU op.
__device__ __forceinline__ unsigned cvt_pk_bf16(float a, float b) {
    unsigned r;
    asm("v_cvt_pk_bf16_f32 %0, %1, %2" : "=v"(r) : "v"(a), "v"(b));
    return r;
}

__device__ __forceinline__ void load_lds16(const void* g, void* l) {
    __builtin_amdgcn_global_load_lds(
        (const __attribute__((address_space(1))) void*)g,
        (__attribute__((address_space(3))) void*)l, 16, 0, 0);
}

// ---------------------------------------------------------------------------
// Gate gemm2 (K=1024), BN=64 tile for 2 blocks/CU (r21: was 1 block/CU at
// BN=128 -> 12.5% occupancy, latency-bound at 27us).
// 128x64 output, 4 waves in 2x2 grid, each 64 rows x 32 cols. F16 state out.
// ---------------------------------------------------------------------------
__global__ __launch_bounds__(256) void gemm2_bn64(
    const __hip_bfloat16* __restrict__ A,   // MM x HH (Whb)
    const __hip_bfloat16* __restrict__ Bt,  // EE x HH (gW2t)
    const float* __restrict__ bias,         // EE
    _Float16* __restrict__ C)               // MM x EE (f16 state)
{
    __shared__ __hip_bfloat16 As[128 * 32];     // 8 KB
    __shared__ __hip_bfloat16 Bs[64 * 32];      // 4 KB

    const int tid = threadIdx.x;
    const int w = tid >> 6, l = tid & 63;
    const int wr = w >> 1, wc = w & 1;          // 2x2; wave tile 64r x 32c
    const int row0 = blockIdx.y * 128;
    const int col0 = blockIdx.x * 64;

    // A staging: 512 chunks, 2 rounds; B staging: 256 chunks, 1 round
    const int c0 = w * 64 + l;
    const int c1 = c0 + 256;
    const __hip_bfloat16* gA0 = A  + (size_t)(row0 + (c0 >> 2)) * HH + (c0 & 3) * 8;
    const __hip_bfloat16* gA1 = A  + (size_t)(row0 + (c1 >> 2)) * HH + (c1 & 3) * 8;
    const __hip_bfloat16* gB0 = Bt + (size_t)(col0 + (c0 >> 2)) * HH + (c0 & 3) * 8;
    char* dA0 = (char*)As + c0 * 16;
    char* dA1 = (char*)As + c1 * 16;
    char* dB0 = (char*)Bs + c0 * 16;

    const int lr = l & 15;
    const int lk = (l >> 4) * 8;

    f32x4 acc[4][2] = {};

    for (int k0 = 0; k0 < HH; k0 += 32) {
        load_lds16(gA0 + k0, dA0);
        load_lds16(gA1 + k0, dA1);
        load_lds16(gB0 + k0, dB0);
        __syncthreads();

        short8 a[4], b[2];
        #pragma unroll
        for (int m = 0; m < 4; ++m)
            a[m] = *(const short8*)&As[(wr * 64 + m * 16 + lr) * 32 + lk];
        #pragma unroll
        for (int n = 0; n < 2; ++n)
            b[n] = *(const short8*)&Bs[(wc * 32 + n * 16 + lr) * 32 + lk];
        #pragma unroll
        for (int m = 0; m < 4; ++m)
            #pragma unroll
            for (int n = 0; n < 2; ++n)
                acc[m][n] = __builtin_amdgcn_mfma_f32_16x16x32_bf16(a[m], b[n], acc[m][n], 0, 0, 0);
        __syncthreads();
    }

    #pragma unroll
    for (int m = 0; m < 4; ++m) {
        #pragma unroll
        for (int n = 0; n < 2; ++n) {
            const int col = col0 + wc * 32 + n * 16 + lr;
            const float bv = bias[col];
            #pragma unroll
            for (int j = 0; j < 4; ++j) {
                const int row = row0 + wr * 64 + m * 16 + (l >> 4) * 4 + j;
                C[(size_t)row * EE + col] = (_Float16)(acc[m][n][j] + bv);
            }
        }
    }
}

// ---------------------------------------------------------------------------
// Gate gemm1, A-in-registers (r14/r16-validated): Wh(bf16) = gelu(Vb@W1+b1).
// ---------------------------------------------------------------------------
__global__ __launch_bounds__(256, 3) void gemm1_areg(
    const __hip_bfloat16* __restrict__ A,     // MM x EE (Vb)
    const __hip_bfloat16* __restrict__ W1t,   // HH x EE
    const float* __restrict__ b1,             // HH
    __hip_bfloat16* __restrict__ Wh)          // MM x HH
{
    __shared__ __hip_bfloat16 Bs[8 * 64 * 32];   // 32 KB [kk][row][32]
    __shared__ __align__(16) char Gb[4][4096];   // per-wave G [32r][64h]

    const int tid = threadIdx.x;
    const int w = tid >> 6, l = tid & 63;
    const int row0 = blockIdx.x * 128;
    const int col0 = blockIdx.y * 128;
    const int lr = l & 15, g = l >> 4, lk = g * 8;

    short8 xf[2][8];
    {
        const __hip_bfloat16* xp0 = A + (size_t)(row0 + w * 32 + lr) * EE + lk;
        #pragma unroll
        for (int kk = 0; kk < 8; ++kk) {
            xf[0][kk] = *(const short8*)(xp0 + kk * 32);
            xf[1][kk] = *(const short8*)(xp0 + 16 * EE + kk * 32);
        }
    }
    char* Gw = Gb[w];

    #pragma unroll
    for (int rstep = 0; rstep < 8; ++rstep) {
        const int c = rstep * 256 + tid;
        load_lds16(W1t + (size_t)(col0 + ((c >> 2) & 63)) * EE + (c >> 8) * 32 + (c & 3) * 8,
                   (char*)Bs + c * 16);
    }
    __syncthreads();

    #pragma unroll 1
    for (int ct = 0; ct < 2; ++ct) {
        f32x4 acc[4][2];
        #pragma unroll
        for (int ni = 0; ni < 4; ++ni) {
            const float4 bv = *(const float4*)&b1[col0 + ct * 64 + ni * 16 + g * 4];
            const f32x4 bi = {bv.x, bv.y, bv.z, bv.w};
            acc[ni][0] = bi;
            acc[ni][1] = bi;
        }
        __builtin_amdgcn_s_setprio(1);
        #pragma unroll
        for (int kk = 0; kk < 8; ++kk) {
            short8 a[4];
            #pragma unroll
            for (int ni = 0; ni < 4; ++ni)
                a[ni] = *(const short8*)((const char*)Bs +
                         (kk * 4096 + ni * 1024 + lr * 64 + g * 16));
            #pragma unroll
            for (int ni = 0; ni < 4; ++ni) {
                acc[ni][0] = __builtin_amdgcn_mfma_f32_16x16x32_bf16(a[ni], xf[0][kk], acc[ni][0], 0, 0, 0);
                acc[ni][1] = __builtin_amdgcn_mfma_f32_16x16x32_bf16(a[ni], xf[1][kk], acc[ni][1], 0, 0, 0);
            }
        }
        __builtin_amdgcn_s_setprio(0);
        __syncthreads();

        if (ct == 0) {
            #pragma unroll
            for (int rstep = 0; rstep < 8; ++rstep) {
                const int c = rstep * 256 + tid;
                load_lds16(W1t + (size_t)(col0 + 64 + ((c >> 2) & 63)) * EE + (c >> 8) * 32 + (c & 3) * 8,
                           (char*)Bs + c * 16);
            }
        }

        // gelu (f32) -> bf16 (cvt_pk) -> wave-private swizzled G
        #pragma unroll
        for (int ni = 0; ni < 4; ++ni) {
            #pragma unroll
            for (int mi = 0; mi < 2; ++mi) {
                const int rloc = mi * 16 + lr;
                const float v0 = gelu_fast(acc[ni][mi][0]);
                const float v1 = gelu_fast(acc[ni][mi][1]);
                const float v2 = gelu_fast(acc[ni][mi][2]);
                const float v3 = gelu_fast(acc[ni][mi][3]);
                uint2 pk;
                pk.x = cvt_pk_bf16(v0, v1);
                pk.y = cvt_pk_bf16(v2, v3);
                const int byte = (rloc * 128 + (ni * 16 + g * 4) * 2) ^ ((rloc & 7) << 4);
                *(uint2*)(Gw + byte) = pk;
            }
        }

        // coalesced store: 4 passes x (8 rows x 128B); G is wave-private
        #pragma unroll
        for (int p = 0; p < 4; ++p) {
            const int rl = p * 8 + (l >> 3);
            const int hb = (l & 7) * 16;
            const uint4 v = *(const uint4*)(Gw + ((rl * 128 + hb) ^ ((rl & 7) << 4)));
            *(uint4*)((char*)(Wh + (size_t)(row0 + w * 32 + rl) * HH + col0 + ct * 64) + hb) = v;
        }
        __syncthreads();
    }
}

// ---------------------------------------------------------------------------
// Fused f-level kernel (r15/r16-validated 138 us), Wall written transposed.
// ---------------------------------------------------------------------------
__global__ __launch_bounds__(256, 3) void f_fused(
    const __hip_bfloat16* __restrict__ X,     // MM x EE (bf16)
    const __hip_bfloat16* __restrict__ W1t,   // NW x HH x EE (bf16)
    const float* __restrict__ b1,             // NW x HH
    const _Float16* __restrict__ W2t,         // NW x 16 x HH (f16)
    const float* __restrict__ b2,             // NW x NL
    float* __restrict__ Wall_t)               // [NW*16][MM]
{
    __shared__ __hip_bfloat16 Bs[8 * 64 * 32];        // 32 KB [kk][row][32]
    __shared__ __align__(16) char Gb[4][4096];        // per-wave G [32r][64h] f16
    __shared__ float biasS[HH];                       // 4 KB

    const int tid = threadIdx.x;
    const int w = tid >> 6, l = tid & 63;
    const int row0 = blockIdx.x * 128;
    const int m_lv = blockIdx.y;
    const int lr = l & 15;
    const int g  = l >> 4;
    const int lk = g * 8;

    const __hip_bfloat16* W1m = W1t + (size_t)m_lv * HH * EE;

    ((float4*)biasS)[tid] = ((const float4*)(b1 + (size_t)m_lv * HH))[tid];

    short8 xf[2][8];
    {
        const __hip_bfloat16* xp0 = X + (size_t)(row0 + w * 32 + lr) * EE + lk;
        #pragma unroll
        for (int kk = 0; kk < 8; ++kk) {
            xf[0][kk] = *(const short8*)(xp0 + kk * 32);
            xf[1][kk] = *(const short8*)(xp0 + 16 * EE + kk * 32);
        }
    }

    const _Float16* w2p = W2t + ((size_t)m_lv * 16 + lr) * HH + lk;
    char* Gw = Gb[w];

    f32x4 wacc0 = {}, wacc1 = {};

    #pragma unroll
    for (int rstep = 0; rstep < 8; ++rstep) {
        const int c = rstep * 256 + tid;
        load_lds16(W1m + (size_t)((c >> 2) & 63) * EE + (c >> 8) * 32 + (c & 3) * 8,
                   (char*)Bs + c * 16);
    }
    __syncthreads();

    #pragma unroll 1
    for (int ct = 0; ct < 16; ++ct) {
        // acc C-in = bias
        f32x4 acc[4][2];
        #pragma unroll
        for (int ni = 0; ni < 4; ++ni) {
            const float4 bv = *(const float4*)&biasS[ct * 64 + ni * 16 + g * 4];
            const f32x4 bi = {bv.x, bv.y, bv.z, bv.w};
            acc[ni][0] = bi;
            acc[ni][1] = bi;
        }
        __builtin_amdgcn_s_setprio(1);
        #pragma unroll
        for (int kk = 0; kk < 8; ++kk) {
            short8 a[4];
            #pragma unroll
            for (int ni = 0; ni < 4; ++ni)
                a[ni] = *(const short8*)((const char*)Bs +
                         (kk * 4096 + ni * 1024 + lr * 64 + g * 16));
            #pragma unroll
            for (int ni = 0; ni < 4; ++ni) {
                acc[ni][0] = __builtin_amdgcn_mfma_f32_16x16x32_bf16(a[ni], xf[0][kk], acc[ni][0], 0, 0, 0);
                acc[ni][1] = __builtin_amdgcn_mfma_f32_16x16x32_bf16(a[ni], xf[1][kk], acc[ni][1], 0, 0, 0);
            }
        }
        __builtin_amdgcn_s_setprio(0);
        __syncthreads();                       // all waves done reading Bs

        if (ct < 15) {
            const __hip_bfloat16* W1n = W1m + (size_t)(ct + 1) * 64 * EE;
            #pragma unroll
            for (int rstep = 0; rstep < 8; ++rstep) {
                const int c = rstep * 256 + tid;
                load_lds16(W1n + (size_t)((c >> 2) & 63) * EE + (c >> 8) * 32 + (c & 3) * 8,
                           (char*)Bs + c * 16);
            }
        }

        // gelu (packed f16) -> wave-private swizzled G (f16)
        #pragma unroll
        for (int ni = 0; ni < 4; ++ni) {
            #pragma unroll
            for (int mi = 0; mi < 2; ++mi) {
                const int rloc = mi * 16 + lr;
                uint2 pk;
                pk.x = gelu2_f16(acc[ni][mi][0], acc[ni][mi][1]);
                pk.y = gelu2_f16(acc[ni][mi][2], acc[ni][mi][3]);
                const int byte = (rloc * 128 + (ni * 16 + g * 4) * 2) ^ ((rloc & 7) << 4);
                *(uint2*)(Gw + byte) = pk;
            }
        }

        // mini-GEMM (f16): Wall-frag += W2t[ct k-range] x G
        #pragma unroll
        for (int ks2 = 0; ks2 < 2; ++ks2) {
            const half8 aw = *(const half8*)(w2p + ct * 64 + ks2 * 32);
            {
                const int byte = (lr * 128 + (ks2 * 32 + lk) * 2) ^ ((lr & 7) << 4);
                const half8 bg = *(const half8*)(Gw + byte);
                wacc0 = __builtin_amdgcn_mfma_f32_16x16x32_f16(aw, bg, wacc0, 0, 0, 0);
            }
            {
                const int rloc = 16 + lr;
                const int byte = (rloc * 128 + (ks2 * 32 + lk) * 2) ^ ((rloc & 7) << 4);
                const half8 bg = *(const half8*)(Gw + byte);
                wacc1 = __builtin_amdgcn_mfma_f32_16x16x32_f16(aw, bg, wacc1, 0, 0, 0);
            }
        }
        __syncthreads();                       // staging drained; Bs ready
    }

    // epilogue -> Wall_t[(m*16 + lval)*MM + r]
    const float* b2m = b2 + m_lv * NL;
    #pragma unroll
    for (int j = 0; j < 4; ++j) {
        const int lval = g * 4 + j;
        const float bv = (lval < NL) ? b2m[lval] : 0.f;
        float* wp = Wall_t + (size_t)(m_lv * 16 + lval) * MM;
        wp[row0 + w * 32 + lr]      = wacc0[j] + bv;
        wp[row0 + w * 32 + 16 + lr] = wacc1[j] + bv;
    }
}

// ---------------------------------------------------------------------------
// One prep kernel for ALL conversions/transposes.
// ---------------------------------------------------------------------------
struct bf4 { __hip_bfloat16 a, b, c, d; };

__device__ __forceinline__ void cvt_body(
    const float* __restrict__ in, __hip_bfloat16* __restrict__ out, int i)
{
    float4 v = ((const float4*)in)[i];
    bf4 o;
    o.a = __float2bfloat16(v.x); o.b = __float2bfloat16(v.y);
    o.c = __float2bfloat16(v.z); o.d = __float2bfloat16(v.w);
    ((bf4*)out)[i] = o;
}

__device__ __forceinline__ void transpose_body(
    const float* __restrict__ inB, __hip_bfloat16* __restrict__ outB,
    int K, int N, int bx, int by, float (*t)[33])
{
    const int n0 = bx * 32, k0 = by * 32;
    const int tx = threadIdx.x & 31, ty = threadIdx.x >> 5;  // 32 x 8
    #pragma unroll
    for (int i = 0; i < 32; i += 8)
        t[ty + i][tx] = inB[(size_t)(k0 + ty + i) * N + n0 + tx];
    __syncthreads();
    #pragma unroll
    for (int i = 0; i < 32; i += 8)
        outB[(size_t)(n0 + ty + i) * K + k0 + tx] = __float2bfloat16(t[tx][ty + i]);
}

__global__ __launch_bounds__(256) void prep_all(
    const float* __restrict__ V, const float* __restrict__ input,
    const float* __restrict__ g_W1, const float* __restrict__ g_W2,
    const float* __restrict__ f_W1, const float* __restrict__ f_W2,
    __hip_bfloat16* __restrict__ Vb, __hip_bfloat16* __restrict__ Xb,
    __hip_bfloat16* __restrict__ gW1t, __hip_bfloat16* __restrict__ gW2t,
    __hip_bfloat16* __restrict__ fW1t, _Float16* __restrict__ W2tA)
{
    __shared__ float t[32][33];
    const int bid = blockIdx.x;
    const int tid = threadIdx.x;

    if (bid < 4096) {
        cvt_body(V, Vb, bid * 256 + tid);
    } else if (bid < 8192) {
        cvt_body(input, Xb, (bid - 4096) * 256 + tid);
    } else if (bid < 8448) {
        const int b2 = bid - 8192;                   // g_W1: grid (32, 8)
        transpose_body(g_W1, gW1t, EE, HH, b2 & 31, b2 >> 5, t);
    } else if (bid < 8704) {
        const int b2 = bid - 8448;                   // g_W2: grid (8, 32)
        transpose_body(g_W2, gW2t, HH, EE, b2 & 7, b2 >> 3, t);
    } else if (bid < 11776) {
        const int b2 = bid - 8704;                   // f_W1: 12 x (32, 8)
        const int z = b2 >> 8, r = b2 & 255;
        transpose_body(f_W1 + (size_t)z * EE * HH, fW1t + (size_t)z * HH * EE,
                       EE, HH, r & 31, r >> 5, t);
    } else {
        const int idx = (bid - 11776) * 256 + tid;   // w2t: NW*16*HH elems, f16
        const int m = idx >> 14;
        const int n = (idx >> 10) & 15;
        const int h = idx & 1023;
        const float v = (n < NL) ? f_W2[((size_t)m * HH + h) * NL + n] : 0.f;
        W2tA[idx] = (_Float16)v;
    }
}

// ---------------------------------------------------------------------------
// ALL 12 chord steps in ONE kernel, PACKED-F16 state resident in LDS
// (r20/r21-validated: 1024 thr, pk-fma state math, absmax 0.0156).
// ---------------------------------------------------------------------------
__global__ __launch_bounds__(1024, 1) void chord_lds(
    const uint2* __restrict__ Vg,     // MM x 64 (2x packed-f16 per slot)
    const float* __restrict__ Wall_t, // [NW*16][MM]
    float4* __restrict__ outF)        // MM x 64 (f32 x4) final output
{
    __shared__ unsigned L[2][2][NN];   // [buf][ch-pair][row]  64 KB

    const int tid = threadIdx.x;       // 0..1023
    const int bid = blockIdx.x;        // 0..255
    const int batch = bid >> 6;
    const int slice = bid & 63;        // 4-channel slice
    const int gbase = batch * NN;

    // init: load own 4 rows from global (f16 x4 per row, already packed)
    #pragma unroll
    for (int i = 0; i < 4; ++i) {
        const int n = tid + i * 1024;
        const uint2 u = Vg[(size_t)(gbase + n) * 64 + slice];
        L[0][0][n] = u.x;
        L[0][1][n] = u.y;
    }
    __syncthreads();

    int cur = 0;
    #pragma unroll 1
    for (int m = 0; m < NW; ++m) {
        const float* wbase = Wall_t + (size_t)m * 16 * MM + gbase;
        const int nxt = cur ^ 1;
        #pragma unroll 1
        for (int i = 0; i < 4; ++i) {
            const int n = tid + i * 1024;
            h2 a01 = __builtin_bit_cast(h2, L[cur][0][n]);
            h2 a23 = __builtin_bit_cast(h2, L[cur][1][n]);
            #pragma unroll
            for (int l = 0; l < NL; ++l) {
                const int off = (l == 0) ? 0 : (1 << (l - 1));
                const int cn = (n + off) & (NN - 1);
                const float wv = wbase[(size_t)l * MM + n];
                const h2 w2 = cvt_pk_f16(wv, wv);
                const h2 x01 = __builtin_bit_cast(h2, L[cur][0][cn]);
                const h2 x23 = __builtin_bit_cast(h2, L[cur][1][cn]);
                a01 = w2 * x01 + a01;          // v_pk_fma_f16
                a23 = w2 * x23 + a23;
            }
            if (m == NW - 1) {
                float4 o = {(float)a01[0], (float)a01[1],
                            (float)a23[0], (float)a23[1]};
                outF[(size_t)(gbase + n) * 64 + slice] = o;
            } else {
                L[nxt][0][n] = __builtin_bit_cast(unsigned, a01);
                L[nxt][1][n] = __builtin_bit_cast(unsigned, a23);
            }
        }
        __syncthreads();
        cur ^= 1;
    }
}

// ---------------------------------------------------------------------------
extern "C" void kernel_launch(void* const* d_in, const int* in_sizes, int n_in,
                              void* d_out, int out_size, void* d_ws, size_t ws_size,
                              hipStream_t stream)
{
    const float* V      = (const float*)d_in[0];
    const float* input  = (const float*)d_in[1];
    const float* g_W1   = (const float*)d_in[2];
    const float* g_b1   = (const float*)d_in[3];
    const float* g_W2   = (const float*)d_in[4];
    const float* g_b2   = (const float*)d_in[5];
    const float* f_W1   = (const float*)d_in[6];
    const float* f_b1   = (const float*)d_in[7];
    const float* f_W2   = (const float*)d_in[8];
    const float* f_b2   = (const float*)d_in[9];
    float* out = (float*)d_out;

    char* ws = (char*)d_ws;
    size_t o = 0;
    __hip_bfloat16* Vb     = (__hip_bfloat16*)(ws + o); o += (size_t)MM * EE * 2;        // 8 MB
    __hip_bfloat16* Xb     = (__hip_bfloat16*)(ws + o); o += (size_t)MM * EE * 2;        // 8 MB
    __hip_bfloat16* gW1t   = (__hip_bfloat16*)(ws + o); o += (size_t)HH * EE * 2;        // 512 KB
    __hip_bfloat16* gW2t   = (__hip_bfloat16*)(ws + o); o += (size_t)EE * HH * 2;        // 512 KB
    __hip_bfloat16* fW1t   = (__hip_bfloat16*)(ws + o); o += (size_t)NW * HH * EE * 2;   // 6 MB
    _Float16*       W2tA   = (_Float16*)(ws + o);       o += (size_t)NW * 16 * HH * 2;   // 384 KB
    __hip_bfloat16* Whb    = (__hip_bfloat16*)(ws + o); o += (size_t)MM * HH * 2;        // 32 MB (gate only)
    float*          Wall   = (float*)(ws + o);          o += (size_t)NW * 16 * MM * 4;   // 12 MB (transposed)
    _Float16*       Vg0    = (_Float16*)(ws + o);       o += (size_t)MM * EE * 2;        // 8 MB (f16 state)

    dim3 blk(256);

    // 0. ALL dtype conversion / weight transposes in one launch
    prep_all<<<12544, blk, 0, stream>>>(V, input, g_W1, g_W2, f_W1, f_W2,
                                        Vb, Xb, gW1t, gW2t, fW1t, W2tA);

    // 1. Gate gemm1: A-in-registers, bf16 output (r14/r16-validated)
    gemm1_areg<<<dim3(MM / 128, HH / 128), blk, 0, stream>>>(Vb, gW1t, g_b1, Whb);
    // 2. Gate gemm2 (K=1024), BN=64 tile -> 512 blocks (2/CU), f16 state out
    gemm2_bn64<<<dim3(EE / 64, MM / 128), blk, 0, stream>>>(Whb, gW2t, g_b2, Vg0);

    // 3. All 12 levels' link weights in ONE fused launch (Wall transposed)
    f_fused<<<dim3(MM / 128, NW), blk, 0, stream>>>(Xb, fW1t, f_b1, W2tA, f_b2, Wall);

    // 4. ALL 12 chord steps in ONE launch, packed-f16 LDS-resident state
    chord_lds<<<256, dim3(1024), 0, stream>>>((const uint2*)Vg0, Wall, (float4*)out);
}